// Round 15
// baseline (361.944 us; speedup 1.0000x reference)
//
#include <hip/hip_runtime.h>
#include <hip/hip_bf16.h>
#include <math.h>

// Problem dims (fixed by reference)
#define BB   256      // batch
#define LDE  64       // desc tokens len
#define NO   10240    // outer nodes
#define LO   32       // x tokens len
#define NM   81920    // mini nodes
#define LM   16       // mini tokens len
#define EO   81920    // outer edges
#define EM   327680   // mini edges
#define ED   128      // embed dim E
#define HIDD 256      // hidden
#define NH   8        // heads
#define DH   16       // head dim
#define VV   10000    // vocab

static inline int nblk(long long n, int b) { return (int)((n + b - 1) / b); }

typedef __attribute__((ext_vector_type(8))) short short8;
typedef __attribute__((ext_vector_type(4))) float f32x4;

// ---- fp32 <-> bf16 (RNE) helpers ----
static __device__ __forceinline__ unsigned short bf16_rne(float f) {
  unsigned u = __float_as_uint(f);
  return (unsigned short)((u + 0x7fffu + ((u >> 16) & 1u)) >> 16);
}
static __device__ __forceinline__ float bf16_to_f(unsigned short h) {
  return __uint_as_float(((unsigned)h) << 16);
}
static __device__ __forceinline__ float4 b4f(ushort4 h) {
  return make_float4(bf16_to_f(h.x), bf16_to_f(h.y), bf16_to_f(h.z), bf16_to_f(h.w));
}
static __device__ __forceinline__ ushort4 f4b(float4 v) {
  return make_ushort4(bf16_rne(v.x), bf16_rne(v.y), bf16_rne(v.z), bf16_rne(v.w));
}

// ============ merged conversion kernel: 6 weights -> split-bf16 frags, 2 tables -> bf16
struct WC { const float* W; int K, M; short8* hi; short8* lo; int base; };
struct WC6 { WC w[6]; };
__global__ void __launch_bounds__(256)
conv_all_k(WC6 wc, const float* __restrict__ t1, unsigned short* __restrict__ o1,
           const float* __restrict__ t2, unsigned short* __restrict__ o2) {
  if (blockIdx.x < 64) {
    int g = blockIdx.x * 256 + threadIdx.x;   // octet id, 0..16383
    int wi = 0;
    #pragma unroll
    for (int i = 1; i < 6; ++i) if (g >= wc.w[i].base) wi = i;
    const WC c = wc.w[wi];
    int idx = g - c.base;
    int lane = idx & 63;
    int nt = (idx >> 6) % (c.M / 16);
    int kb = (idx >> 6) / (c.M / 16);
    int n = nt * 16 + (lane & 15);
    int k0 = kb * 32 + ((lane >> 4) << 3);
    short8 h, l;
    #pragma unroll
    for (int j = 0; j < 8; ++j) {
      float v = c.W[(size_t)(k0 + j) * c.M + n];
      unsigned short hb = bf16_rne(v);
      h[j] = (short)hb;
      l[j] = (short)bf16_rne(v - bf16_to_f(hb));
    }
    c.hi[idx] = h; c.lo[idx] = l;
  } else {
    int q = (blockIdx.x - 64) * 256 + threadIdx.x;   // quad id
    const int NT = VV * ED / 4;                       // 320000 per table
    if (q < NT) {
      float4 v = *(const float4*)(t1 + (size_t)q * 4);
      *(ushort4*)(o1 + (size_t)q * 4) = f4b(v);
    } else if (q < 2 * NT) {
      int q2 = q - NT;
      float4 v = *(const float4*)(t2 + (size_t)q2 * 4);
      *(ushort4*)(o2 + (size_t)q2 * 4) = f4b(v);
    }
  }
}

// ---- embedding masked mean body: 256 thr = 8 rows x 32 4-elem lanes ----
template<int L, bool TBF, bool OUTBF>
static __device__ __forceinline__ void embed_body(const int* __restrict__ tokens,
                                                  const void* __restrict__ table,
                                                  void* __restrict__ out, int blk) {
  const int r = threadIdx.x >> 5, lane = threadIdx.x & 31;
  const int n0 = blk * 8;
  __shared__ int toks[8][L];
  for (int i = threadIdx.x; i < 8 * L; i += 256)
    toks[i / L][i % L] = tokens[(size_t)n0 * L + i];
  __syncthreads();
  float4 acc = make_float4(0.f, 0.f, 0.f, 0.f);
  int cnt = 0;
  #pragma unroll
  for (int l = 0; l < L; ++l) {
    int t = toks[r][l];
    float4 v;
    if (TBF) v = b4f(*((const ushort4*)((const unsigned short*)table + (size_t)t * ED + lane * 4)));
    else     v = *(const float4*)((const float*)table + (size_t)t * ED + lane * 4);
    float msk = (t != 0) ? 1.f : 0.f;
    cnt += (t != 0);
    acc.x = fmaf(msk, v.x, acc.x); acc.y = fmaf(msk, v.y, acc.y);
    acc.z = fmaf(msk, v.z, acc.z); acc.w = fmaf(msk, v.w, acc.w);
  }
  float inv = 1.f / (float)(cnt > 0 ? cnt : 1);
  acc.x *= inv; acc.y *= inv; acc.z *= inv; acc.w *= inv;
  if (OUTBF)
    *(ushort4*)((unsigned short*)out + (size_t)(n0 + r) * ED + lane * 4) = f4b(acc);
  else
    *(float4*)((float*)out + (size_t)(n0 + r) * ED + lane * 4) = acc;
}

// all three embeddings in one launch
__global__ void __launch_bounds__(256)
embed_all_k(const int* __restrict__ desc_tokens, const float* __restrict__ desc_table,
            float* __restrict__ h_n,
            const int* __restrict__ x_tokens, const unsigned short* __restrict__ ctab2,
            unsigned short* __restrict__ stmt,
            const int* __restrict__ mini_tokens, const unsigned short* __restrict__ ctab,
            unsigned short* __restrict__ miniE) {
  int b = blockIdx.x;
  if (b < BB / 8) embed_body<LDE, false, false>(desc_tokens, desc_table, h_n, b);
  else if (b < BB / 8 + NO / 8) embed_body<LO, true, true>(x_tokens, ctab2, stmt, b - BB / 8);
  else embed_body<LM, true, true>(mini_tokens, ctab, miniE, b - BB / 8 - NO / 8);
}

// ========== QKVS GEMM v7: XCD-aware swizzle, single-term, 512 thr ==========
struct QDesc { const short8* bh; const float* bias; unsigned short* C; };
struct QDesc4 { QDesc d[4]; };

__global__ void __launch_bounds__(512)
mgemm_qkvs7_k(const unsigned short* __restrict__ Ab, QDesc4 g4) {
  const int id = blockIdx.x;
  const int mat = (id >> 3) & 3;
  const int rowb = (id & 7) | ((id >> 5) << 3);
  const QDesc d = g4.d[mat];
  const int n0 = rowb * 128;
  const int tid = threadIdx.x;
  const int w = tid >> 6, lane = tid & 63;
  const int wm = (w & 3) * 2;
  const int wn = (w >> 2) * 4;
  const int r = lane & 15, qd = lane >> 4;
  f32x4 acc[2][4];
  #pragma unroll
  for (int i = 0; i < 2; ++i)
    #pragma unroll
    for (int j = 0; j < 4; ++j) acc[i][j] = (f32x4){0.f, 0.f, 0.f, 0.f};
  #pragma unroll
  for (int kb = 0; kb < 4; ++kb) {
    short8 bh[4];
    #pragma unroll
    for (int j = 0; j < 4; ++j)
      bh[j] = d.bh[((size_t)kb * 8 + wn + j) * 64 + lane];
    short8 a[2];
    #pragma unroll
    for (int i = 0; i < 2; ++i)
      a[i] = *(const short8*)(Ab + (size_t)(n0 + (wm + i) * 16 + r) * ED + kb * 32 + qd * 8);
    #pragma unroll
    for (int i = 0; i < 2; ++i)
      #pragma unroll
      for (int j = 0; j < 4; ++j)
        acc[i][j] = __builtin_amdgcn_mfma_f32_16x16x32_bf16(a[i], bh[j], acc[i][j], 0, 0, 0);
  }
  #pragma unroll
  for (int i = 0; i < 2; ++i)
    #pragma unroll
    for (int j = 0; j < 4; ++j) {
      int col = (wn + j) * 16 + r;
      float bv = d.bias[col];
      #pragma unroll
      for (int rr = 0; rr < 4; ++rr) {
        int row = (wm + i) * 16 + qd * 4 + rr;
        d.C[(size_t)(n0 + row) * ED + col] = bf16_rne(acc[i][j][rr] + bv);
      }
    }
}

// ========== generic single-term bf16 GEMM: bf16 A (row-major) x frag-W -> bf16 C ======
template<bool RELU>
__global__ void __launch_bounds__(512)
mgemm_b_k(const unsigned short* __restrict__ Ab, const short8* __restrict__ Bh,
          const float* __restrict__ bias, unsigned short* __restrict__ C,
          int K, int M) {
  const int bn0 = blockIdx.x * 128;
  const int n0 = blockIdx.y * 128;
  const int tid = threadIdx.x;
  const int w = tid >> 6, lane = tid & 63;
  const int wm = (w & 3) * 2, wn = (w >> 2) * 4;
  const int r = lane & 15, qd = lane >> 4;
  const int NTm = M / 16;
  f32x4 acc[2][4];
  #pragma unroll
  for (int i = 0; i < 2; ++i)
    #pragma unroll
    for (int j = 0; j < 4; ++j) acc[i][j] = (f32x4){0.f, 0.f, 0.f, 0.f};
  const int kbn = K / 32;
  for (int kb = 0; kb < kbn; ++kb) {
    short8 bh[4];
    #pragma unroll
    for (int j = 0; j < 4; ++j)
      bh[j] = Bh[((size_t)kb * NTm + (bn0 >> 4) + wn + j) * 64 + lane];
    short8 a[2];
    #pragma unroll
    for (int i = 0; i < 2; ++i)
      a[i] = *(const short8*)(Ab + (size_t)(n0 + (wm + i) * 16 + r) * K + kb * 32 + qd * 8);
    #pragma unroll
    for (int i = 0; i < 2; ++i)
      #pragma unroll
      for (int j = 0; j < 4; ++j)
        acc[i][j] = __builtin_amdgcn_mfma_f32_16x16x32_bf16(a[i], bh[j], acc[i][j], 0, 0, 0);
  }
  #pragma unroll
  for (int i = 0; i < 2; ++i)
    #pragma unroll
    for (int j = 0; j < 4; ++j) {
      int col = bn0 + (wn + j) * 16 + r;
      float bv = bias ? bias[col] : 0.f;
      #pragma unroll
      for (int rr = 0; rr < 4; ++rr) {
        int row = n0 + (wm + i) * 16 + qd * 4 + rr;
        float v = acc[i][j][rr] + bv;
        if (RELU) v = fmaxf(v, 0.f);
        C[(size_t)row * M + col] = bf16_rne(v);
      }
    }
}

// ================= CSR build (merged scan chain) =================
__global__ void hist2_k(const int* __restrict__ dm, int* __restrict__ hm,
                        const int* __restrict__ dd, int* __restrict__ ho) {
  int e = blockIdx.x * 256 + threadIdx.x;
  if (e < EM) atomicAdd(&hm[dm[e]], 1);
  else { int e2 = e - EM; if (e2 < EO) atomicAdd(&ho[dd[e2]], 1); }
}
__global__ void chunk_sum_k(const int* __restrict__ hist, int* __restrict__ partials, int N) {
  __shared__ int sd[256];
  int i = blockIdx.x * 256 + threadIdx.x;
  sd[threadIdx.x] = (i < N) ? hist[i] : 0;
  __syncthreads();
  for (int s = 128; s > 0; s >>= 1) {
    if (threadIdx.x < s) sd[threadIdx.x] += sd[threadIdx.x + s];
    __syncthreads();
  }
  if (threadIdx.x == 0) partials[blockIdx.x] = sd[0];
}
__global__ void scan_partials2_k(int* __restrict__ p) {
  __shared__ int sd[512];
  int base = (blockIdx.x == 0) ? 0 : NM / 256;
  int B    = (blockIdx.x == 0) ? NM / 256 : NO / 256;
  int t = threadIdx.x;
  int v = (t < B) ? p[base + t] : 0;
  sd[t] = v; __syncthreads();
  for (int off = 1; off < 512; off <<= 1) {
    int a = (t >= off) ? sd[t - off] : 0;
    __syncthreads();
    sd[t] += a;
    __syncthreads();
  }
  if (t < B) p[base + t] = sd[t] - v;   // exclusive
}
__global__ void scan_final2_k(const int* __restrict__ hist, const int* __restrict__ partials,
                              int* __restrict__ offsm, int* __restrict__ curm,
                              int* __restrict__ offso, int* __restrict__ curo,
                              float* __restrict__ dinv) {
  __shared__ int sd[256];
  int i = blockIdx.x * 256 + threadIdx.x;
  int v = hist[i];
  sd[threadIdx.x] = v; __syncthreads();
  for (int off = 1; off < 256; off <<= 1) {
    int a = (threadIdx.x >= off) ? sd[threadIdx.x - off] : 0;
    __syncthreads();
    sd[threadIdx.x] += a;
    __syncthreads();
  }
  int excl = sd[threadIdx.x] - v + partials[blockIdx.x];
  if (i < NM) {
    offsm[i] = excl; curm[i] = excl;
    if (i == NM - 1) offsm[NM] = excl + v;
  } else {
    int i2 = i - NM;
    offso[i2] = excl; curo[i2] = excl;
    if (i2 == NO - 1) offso[NO] = excl + v;
    dinv[i2] = 1.f / sqrtf(1.f + (float)v);
  }
}
__global__ void scatter2_k(const int* __restrict__ sm, const int* __restrict__ dm,
                           int* __restrict__ cm, int* __restrict__ km,
                           const int* __restrict__ so, const int* __restrict__ dd,
                           int* __restrict__ co, int* __restrict__ ko) {
  int e = blockIdx.x * 256 + threadIdx.x;
  if (e < EM) {
    int pos = atomicAdd(&cm[dm[e]], 1);
    km[pos] = sm[e];
  } else {
    int e2 = e - EM;
    if (e2 < EO) {
      int pos = atomicAdd(&co[dd[e2]], 1);
      ko[pos] = so[e2];
    }
  }
}

// ============ fused TransformerConv: FULL WAVE per node, dual-half edge streams ======
// 256 thr = 4 waves = 4 nodes. Lane-half h processes edges base+2i+h (4-chunked ->
// 8 gathers in flight per wave). Two online-softmax states merged via xor-32 shuffles.
// NaN guard: when mn==-inf (empty state AND padded edge) force scale=1, pe=0 — the
// exact no-op. (R14 bug: degree-1 nodes gave half-1 an all-padded stream ->
// expf(-inf - -inf) = NaN poisoned the merge via NaN*0.)
__global__ void __launch_bounds__(256)
attn_fused_k(unsigned short* qh, const unsigned short* __restrict__ kk,
             const unsigned short* __restrict__ vv, const unsigned short* __restrict__ skip,
             const int* __restrict__ offs, const int* __restrict__ csr,
             const float* __restrict__ Wg, const float* __restrict__ bg,
             float* __restrict__ gateOut) {
  const int wv = threadIdx.x >> 6, lane = threadIdx.x & 63;
  const int half = lane >> 5, cl = lane & 31;
  const int n = blockIdx.x * 4 + wv;
  float4 q = b4f(*(const ushort4*)(qh + (size_t)n * ED + cl * 4));
  int lo = offs[n], hi = offs[n + 1];
  float4 O = make_float4(0.f, 0.f, 0.f, 0.f);
  float m = -INFINITY, l = 0.f;
  for (int base = lo; base < hi; base += 8) {
    int sidx[4]; bool ok[4];
    #pragma unroll
    for (int i = 0; i < 4; ++i) {
      int e = base + 2 * i + half;
      ok[i] = e < hi;
      sidx[i] = ok[i] ? csr[e] : 0;
    }
    ushort4 kr[4], vr[4];
    #pragma unroll
    for (int i = 0; i < 4; ++i) {
      kr[i] = *(const ushort4*)(kk + (size_t)sidx[i] * ED + cl * 4);
      vr[i] = *(const ushort4*)(vv + (size_t)sidx[i] * ED + cl * 4);
    }
    #pragma unroll
    for (int i = 0; i < 4; ++i) {
      float4 kt = b4f(kr[i]);
      float4 vt = b4f(vr[i]);
      float p = q.x * kt.x + q.y * kt.y + q.z * kt.z + q.w * kt.w;
      p += __shfl_xor(p, 1, 64);     // stays within the 4-lane head group
      p += __shfl_xor(p, 2, 64);
      float sc = ok[i] ? p * 0.25f : -INFINITY;   // 1/sqrt(Dh); pad = no-op
      float mn = fmaxf(m, sc);
      bool dead = (mn == -INFINITY);              // empty state + padded edge
      float scale = dead ? 1.f : __expf(m - mn);
      float pe    = dead ? 0.f : __expf(sc - mn);
      l = l * scale + pe;
      O.x = O.x * scale + pe * vt.x; O.y = O.y * scale + pe * vt.y;
      O.z = O.z * scale + pe * vt.z; O.w = O.w * scale + pe * vt.w;
      m = mn;
    }
  }
  // merge the two half-states (flash 2-way merge); guard empty states (m=-inf)
  float m1 = __shfl_xor(m, 32, 64);
  float l1 = __shfl_xor(l, 32, 64);
  float4 O1 = make_float4(__shfl_xor(O.x, 32, 64), __shfl_xor(O.y, 32, 64),
                          __shfl_xor(O.z, 32, 64), __shfl_xor(O.w, 32, 64));
  float mm = fmaxf(m, m1);
  float a0 = (m  == -INFINITY) ? 0.f : __expf(m  - mm);
  float a1 = (m1 == -INFINITY) ? 0.f : __expf(m1 - mm);
  float lt = l * a0 + l1 * a1;
  float4 Ot = make_float4(O.x * a0 + O1.x * a1, O.y * a0 + O1.y * a1,
                          O.z * a0 + O1.z * a1, O.w * a0 + O1.w * a1);
  float inv = 1.f / (lt + 1e-16f);
  float4 sk = b4f(*(const ushort4*)(skip + (size_t)n * ED + cl * 4));
  float4 out = make_float4(Ot.x * inv + sk.x, Ot.y * inv + sk.y,
                           Ot.z * inv + sk.z, Ot.w * inv + sk.w);
  if (half == 0)
    *(ushort4*)(qh + (size_t)n * ED + cl * 4) = f4b(out);
  float4 wg = *(const float4*)(Wg + cl * 4);
  float ps = out.x * wg.x + out.y * wg.y + out.z * wg.z + out.w * wg.w;
  #pragma unroll
  for (int o = 1; o <= 16; o <<= 1) ps += __shfl_xor(ps, o, 64);  // within 32-half
  if (lane == 0) gateOut[n] = ps + bg[0];
}

// ============ GCN gather (bf16): FULL WAVE per node, dual-half edge streams ============
__global__ void __launch_bounds__(256)
gcn_gather_b_k(const unsigned short* __restrict__ x, const float* __restrict__ dinv,
               const int* __restrict__ offs, const int* __restrict__ csr,
               const float* __restrict__ bias, unsigned short* __restrict__ out,
               const float* __restrict__ Wg, const float* __restrict__ bg,
               float* __restrict__ gateOut) {
  const int wv = threadIdx.x >> 6, lane = threadIdx.x & 63;
  const int half = lane >> 5, cl = lane & 31;
  const int n = blockIdx.x * 4 + wv;
  float di = dinv[n];
  float4 acc = make_float4(0.f, 0.f, 0.f, 0.f);
  if (half == 0) {   // self term once
    float4 xs = b4f(*(const ushort4*)(x + (size_t)n * ED + cl * 4));
    float w0 = di * di;
    acc = make_float4(w0 * xs.x, w0 * xs.y, w0 * xs.z, w0 * xs.w);
  }
  int lo = offs[n], hi = offs[n + 1];
  for (int base = lo; base < hi; base += 8) {
    int sidx[4]; bool ok[4];
    #pragma unroll
    for (int i = 0; i < 4; ++i) {
      int e = base + 2 * i + half;
      ok[i] = e < hi;
      sidx[i] = ok[i] ? csr[e] : 0;
    }
    float dw[4];
    #pragma unroll
    for (int i = 0; i < 4; ++i) dw[i] = ok[i] ? di * dinv[sidx[i]] : 0.f;
    ushort4 vr[4];
    #pragma unroll
    for (int i = 0; i < 4; ++i)
      vr[i] = *(const ushort4*)(x + (size_t)sidx[i] * ED + cl * 4);
    #pragma unroll
    for (int i = 0; i < 4; ++i) {
      float4 v = b4f(vr[i]);
      acc.x = fmaf(dw[i], v.x, acc.x); acc.y = fmaf(dw[i], v.y, acc.y);
      acc.z = fmaf(dw[i], v.z, acc.z); acc.w = fmaf(dw[i], v.w, acc.w);
    }
  }
  // merge halves
  acc.x += __shfl_xor(acc.x, 32, 64); acc.y += __shfl_xor(acc.y, 32, 64);
  acc.z += __shfl_xor(acc.z, 32, 64); acc.w += __shfl_xor(acc.w, 32, 64);
  if (bias) {
    float4 b4 = *(const float4*)(bias + cl * 4);
    acc.x += b4.x; acc.y += b4.y; acc.z += b4.z; acc.w += b4.w;
  }
  if (half == 0)
    *(ushort4*)(out + (size_t)n * ED + cl * 4) = f4b(acc);
  if (gateOut) {
    float4 wg = *(const float4*)(Wg + cl * 4);
    float ps = acc.x * wg.x + acc.y * wg.y + acc.z * wg.z + acc.w * wg.w;
    #pragma unroll
    for (int o = 1; o <= 16; o <<= 1) ps += __shfl_xor(ps, o, 64);
    if (lane == 0) gateOut[n] = ps + bg[0];
  }
}

// ============ global attention mini->NO (bf16 x/other/out) + combine ============
static __device__ __forceinline__ int lower_bound_d(const int* a, int n, int key) {
  int lo = 0, hi = n;
  while (lo < hi) { int mid = (lo + hi) >> 1; if (a[mid] < key) lo = mid + 1; else hi = mid; }
  return lo;
}
__global__ void __launch_bounds__(128)
gattn_comb_b_k(const unsigned short* __restrict__ xv, const float* __restrict__ gate,
               const int* __restrict__ seg, int Ntot,
               const unsigned short* __restrict__ other, unsigned short* __restrict__ out) {
  const int g = threadIdx.x >> 5, lane = threadIdx.x & 31;
  const int n = blockIdx.x * 4 + g;
  __shared__ int sh[4][2];
  if (lane == 0) {
    sh[g][0] = lower_bound_d(seg, Ntot, n);
    sh[g][1] = lower_bound_d(seg, Ntot, n + 1);
  }
  __syncthreads();
  int lo = sh[g][0], hi = sh[g][1];
  float m = -INFINITY;
  for (int j = lo; j < hi; ++j) m = fmaxf(m, gate[j]);
  float ssum = 0.f;
  for (int j = lo; j < hi; ++j) ssum += __expf(gate[j] - m);
  float inv = 1.f / (ssum + 1e-16f);
  float4 acc = make_float4(0.f, 0.f, 0.f, 0.f);
  for (int j = lo; j < hi; ++j) {
    float a = __expf(gate[j] - m) * inv;
    float4 v = b4f(*(const ushort4*)(xv + (size_t)j * ED + lane * 4));
    acc.x = fmaf(a, v.x, acc.x); acc.y = fmaf(a, v.y, acc.y);
    acc.z = fmaf(a, v.z, acc.z); acc.w = fmaf(a, v.w, acc.w);
  }
  float4 o4 = b4f(*(const ushort4*)(other + (size_t)n * ED + lane * 4));
  acc.x = (acc.x + o4.x) * 0.5f; acc.y = (acc.y + o4.y) * 0.5f;
  acc.z = (acc.z + o4.z) * 0.5f; acc.w = (acc.w + o4.w) * 0.5f;
  *(ushort4*)(out + (size_t)n * ED + lane * 4) = f4b(acc);
}

// ============ final global attention NO->BB (bf16 x) with cosine fused ====
__global__ void __launch_bounds__(128)
gattn_cos_k(const unsigned short* __restrict__ x, const float* __restrict__ gate,
            const int* __restrict__ seg, int Ntot,
            const float* __restrict__ hn, float* __restrict__ outp) {
  const int g = threadIdx.x >> 5, lane = threadIdx.x & 31;
  const int n = blockIdx.x * 4 + g;
  __shared__ int sh[4][2];
  if (lane == 0) {
    sh[g][0] = lower_bound_d(seg, Ntot, n);
    sh[g][1] = lower_bound_d(seg, Ntot, n + 1);
  }
  __syncthreads();
  int lo = sh[g][0], hi = sh[g][1];
  float m = -INFINITY;
  for (int j = lo; j < hi; ++j) m = fmaxf(m, gate[j]);
  float ssum = 0.f;
  for (int j = lo; j < hi; ++j) ssum += __expf(gate[j] - m);
  float inv = 1.f / (ssum + 1e-16f);
  float4 acc = make_float4(0.f, 0.f, 0.f, 0.f);
  for (int j = lo; j < hi; ++j) {
    float a = __expf(gate[j] - m) * inv;
    float4 v = b4f(*(const ushort4*)(x + (size_t)j * ED + lane * 4));
    acc.x = fmaf(a, v.x, acc.x); acc.y = fmaf(a, v.y, acc.y);
    acc.z = fmaf(a, v.z, acc.z); acc.w = fmaf(a, v.w, acc.w);
  }
  float4 hv = *(const float4*)(hn + (size_t)n * ED + lane * 4);
  float dot = acc.x * hv.x + acc.y * hv.y + acc.z * hv.z + acc.w * hv.w;
  float na  = acc.x * acc.x + acc.y * acc.y + acc.z * acc.z + acc.w * acc.w;
  float nb  = hv.x * hv.x + hv.y * hv.y + hv.z * hv.z + hv.w * hv.w;
  #pragma unroll
  for (int o = 1; o <= 16; o <<= 1) {
    dot += __shfl_xor(dot, o, 64);
    na  += __shfl_xor(na,  o, 64);
    nb  += __shfl_xor(nb,  o, 64);
  }
  if (lane == 0)
    outp[n] = dot / (fmaxf(sqrtf(na), 1e-8f) * fmaxf(sqrtf(nb), 1e-8f));
}

// ---- workspace layout (4-byte element offsets) ----
constexpr size_t OFF_HN    = 0;                                  // BB*ED
constexpr size_t OFF_STMT  = OFF_HN    + (size_t)BB * ED;        // NO*ED (bf16 in half)
constexpr size_t OFF_A     = OFF_STMT  + (size_t)NO * ED;        // NM*ED (miniE bf16 -> recycled)
constexpr size_t OFF_QHID  = OFF_A     + (size_t)NM * ED;        // NM*ED floats (bf16 q->hid in 1st half)
constexpr size_t OFF_CT    = OFF_QHID  + (size_t)NM * ED / 2;    // 2nd half of QHID: bf16 tables
constexpr size_t OFF_K     = OFF_QHID  + (size_t)NM * ED;        // NM*ED floats (bf16 k + bf16 skip)
constexpr size_t OFF_V     = OFF_K     + (size_t)NM * ED;        // NM*ED floats (bf16 v in 1st half)
constexpr size_t T0        = OFF_V     + (size_t)NM * ED;
constexpr size_t OFF_GATE  = T0;                                 // NM
constexpr size_t OFF_GATE2 = OFF_GATE  + (size_t)NM;             // NO
constexpr size_t OFF_DINV  = OFF_GATE2 + (size_t)NO;             // NO
constexpr size_t OFF_HISTM = OFF_DINV  + (size_t)NO;             // NM (int)
constexpr size_t OFF_HISTO = OFF_HISTM + (size_t)NM;             // NO (adjacent -> concat scan)
constexpr size_t OFF_OFFSM = OFF_HISTO + (size_t)NO;             // NM+1
constexpr size_t OFF_CURM  = OFF_OFFSM + (size_t)NM + 1;         // NM
constexpr size_t OFF_CSRM  = OFF_CURM  + (size_t)NM;             // EM
constexpr size_t OFF_OFFSO = OFF_CSRM  + (size_t)EM;             // NO+1
constexpr size_t OFF_CURO  = OFF_OFFSO + (size_t)NO + 1;         // NO
constexpr size_t OFF_CSRO  = OFF_CURO  + (size_t)NO;             // EO
constexpr size_t OFF_PART  = OFF_CSRO  + (size_t)EO;             // 512 (int)
constexpr size_t OFF_WFHI  = OFF_PART  + 512;                    // 65536 floats
constexpr size_t OFF_WFLO  = OFF_WFHI  + 65536;                  // 65536 floats
constexpr size_t WO_Q  = 0, WO_K = 2048, WO_V = 4096, WO_S = 6144, WO_W2 = 8192, WO_W3 = 12288;
// region-A recycling after attn (miniE dead): all bf16
constexpr size_t OFF_MFN   = OFF_A;                              // NO*ED (bf16)
constexpr size_t OFF_AGG   = OFF_MFN   + (size_t)NO * ED;        // NO*ED (bf16)
constexpr size_t OFF_H     = OFF_AGG   + (size_t)NO * ED;        // NO*HIDD (bf16)
constexpr size_t OFF_T     = OFF_H     + (size_t)NO * HIDD;      // NO*ED (bf16)
constexpr size_t OFF_FIN   = OFF_T     + (size_t)NO * ED;        // NO*ED (bf16)

extern "C" void kernel_launch(void* const* d_in, const int* in_sizes, int n_in,
                              void* d_out, int out_size, void* d_ws, size_t ws_size,
                              hipStream_t stream) {
  const int* desc_tokens = (const int*)d_in[0];
  const int* x_tokens    = (const int*)d_in[1];
  const int* mini_tokens = (const int*)d_in[2];
  const int* src         = (const int*)d_in[3];
  const int* dst         = (const int*)d_in[4];
  const int* mini_src    = (const int*)d_in[5];
  const int* mini_dst    = (const int*)d_in[6];
  const int* mini_batch  = (const int*)d_in[7];
  const int* node_batch  = (const int*)d_in[8];
  const float* desc_table  = (const float*)d_in[9];
  const float* code_table  = (const float*)d_in[10];
  const float* code_table2 = (const float*)d_in[11];
  const float* Wq = (const float*)d_in[12]; const float* bq = (const float*)d_in[13];
  const float* Wk = (const float*)d_in[14]; const float* bk = (const float*)d_in[15];
  const float* Wv = (const float*)d_in[16]; const float* bv = (const float*)d_in[17];
  const float* Wskip = (const float*)d_in[18]; const float* bskip = (const float*)d_in[19];
  const float* W2 = (const float*)d_in[20]; const float* b2 = (const float*)d_in[21];
  const float* W3 = (const float*)d_in[22]; const float* b3 = (const float*)d_in[23];
  const float* Wg = (const float*)d_in[24]; const float* bg = (const float*)d_in[25];

  float* ws = (float*)d_ws;
  float* h_n   = ws + OFF_HN;
  unsigned short* stmt_b  = (unsigned short*)(ws + OFF_STMT);
  unsigned short* miniE_b = (unsigned short*)(ws + OFF_A);    // bf16 [NM][128]
  unsigned short* qhid_b = (unsigned short*)(ws + OFF_QHID);  // q -> hid, bf16
  unsigned short* ctab_b  = (unsigned short*)(ws + OFF_CT);
  unsigned short* ctab2_b = (unsigned short*)(ws + OFF_CT + (size_t)VV * ED / 2);
  unsigned short* kbuf_b = (unsigned short*)(ws + OFF_K);     // k, bf16
  unsigned short* skip_b = kbuf_b + (size_t)NM * ED;          // skip, bf16 (2nd half)
  unsigned short* vbuf_b = (unsigned short*)(ws + OFF_V);     // v, bf16
  float* gate  = ws + OFF_GATE;
  float* gate2 = ws + OFF_GATE2;
  float* dinv  = ws + OFF_DINV;
  int* histm = (int*)(ws + OFF_HISTM);
  int* histo = (int*)(ws + OFF_HISTO);
  int* offsm = (int*)(ws + OFF_OFFSM);
  int* curm  = (int*)(ws + OFF_CURM);
  int* csrm  = (int*)(ws + OFF_CSRM);
  int* offso = (int*)(ws + OFF_OFFSO);
  int* curo  = (int*)(ws + OFF_CURO);
  int* csro  = (int*)(ws + OFF_CSRO);
  int* part  = (int*)(ws + OFF_PART);
  short8* wfhi = (short8*)(ws + OFF_WFHI);
  short8* wflo = (short8*)(ws + OFF_WFLO);
  unsigned short* mini_fn_b = (unsigned short*)(ws + OFF_MFN);
  unsigned short* aggb_b    = (unsigned short*)(ws + OFF_AGG);
  unsigned short* hbuf_b    = (unsigned short*)(ws + OFF_H);
  unsigned short* tbuf_b    = (unsigned short*)(ws + OFF_T);
  unsigned short* finalS_b  = (unsigned short*)(ws + OFF_FIN);
  float* outp    = (float*)d_out;

  // ---- all conversions in ONE launch: 6 weights + 2 tables ----
  WC6 wc;
  wc.w[0] = {Wq,    ED,   ED,   wfhi + WO_Q,  wflo + WO_Q,  (int)WO_Q};
  wc.w[1] = {Wk,    ED,   ED,   wfhi + WO_K,  wflo + WO_K,  (int)WO_K};
  wc.w[2] = {Wv,    ED,   ED,   wfhi + WO_V,  wflo + WO_V,  (int)WO_V};
  wc.w[3] = {Wskip, ED,   ED,   wfhi + WO_S,  wflo + WO_S,  (int)WO_S};
  wc.w[4] = {W2,    ED,   HIDD, wfhi + WO_W2, wflo + WO_W2, (int)WO_W2};
  wc.w[5] = {W3,    HIDD, ED,   wfhi + WO_W3, wflo + WO_W3, (int)WO_W3};
  conv_all_k<<<64 + nblk(2 * VV * ED / 4, 256), 256, 0, stream>>>(
      wc, code_table, ctab_b, code_table2, ctab2_b);

  // ---- CSR build: merged hist/scatter + single concat scan chain + fused dinv ----
  hipMemsetAsync(histm, 0, (size_t)(NM + NO) * 4, stream);
  hist2_k<<<nblk(EM + EO, 256), 256, 0, stream>>>(mini_dst, histm, dst, histo);
  chunk_sum_k<<<(NM + NO) / 256, 256, 0, stream>>>(histm, part, NM + NO);
  scan_partials2_k<<<2, 512, 0, stream>>>(part);
  scan_final2_k<<<(NM + NO) / 256, 256, 0, stream>>>(histm, part, offsm, curm,
                                                     offso, curo, dinv);
  scatter2_k<<<nblk(EM + EO, 256), 256, 0, stream>>>(mini_src, mini_dst, curm, csrm,
                                                     src, dst, curo, csro);

  // ---- all three embeddings in one launch ----
  embed_all_k<<<BB / 8 + NO / 8 + NM / 8, 256, 0, stream>>>(
      desc_tokens, desc_table, h_n, x_tokens, ctab2_b, stmt_b,
      mini_tokens, ctab_b, miniE_b);

  // ---- Q,K,V,Skip projections: single-term bf16 MFMA, XCD-swizzled 1D grid ----
  QDesc4 g4;
  g4.d[0] = {wfhi + WO_Q, bq,    qhid_b};
  g4.d[1] = {wfhi + WO_K, bk,    kbuf_b};
  g4.d[2] = {wfhi + WO_V, bv,    vbuf_b};
  g4.d[3] = {wfhi + WO_S, bskip, skip_b};
  mgemm_qkvs7_k<<<4 * (NM / 128), 512, 0, stream>>>(miniE_b, g4);

  // ---- fused transformer conv (full wave/node, dual-half streams) + gate ----
  attn_fused_k<<<NM / 4, 256, 0, stream>>>(qhid_b, kbuf_b, vbuf_b, skip_b,
                                           offsm, csrm, Wg, bg, gate);

  // ---- global attention mini -> NO, fused with (x + stmt)*0.5 (all bf16) ----
  gattn_comb_b_k<<<NO / 4, 128, 0, stream>>>(qhid_b, gate, mini_batch, NM,
                                             stmt_b, mini_fn_b);

  // ---- GCN conv 1: agg = A_hat * mini_fn (bf16) ; h = relu(agg @ W2 + b2) (bf16) ----
  gcn_gather_b_k<<<NO / 4, 256, 0, stream>>>(mini_fn_b, dinv, offso, csro, nullptr,
                                             aggb_b, nullptr, nullptr, nullptr);
  { dim3 g(HIDD / 128, NO / 128);
    mgemm_b_k<true><<<g, 512, 0, stream>>>(aggb_b, wfhi + WO_W2, b2, hbuf_b, ED, HIDD); }

  // ---- GCN conv 2: t = h @ W3 (bf16) ; final = A_hat * t + b3 (+ gate2) ----
  { dim3 g(1, NO / 128);
    mgemm_b_k<false><<<g, 512, 0, stream>>>(hbuf_b, wfhi + WO_W3, nullptr, tbuf_b, HIDD, ED); }
  gcn_gather_b_k<<<NO / 4, 256, 0, stream>>>(tbuf_b, dinv, offso, csro, b3, finalS_b,
                                             Wg, bg, gate2);

  // ---- global attention NO -> BB with fused cosine -> d_out [BB] ----
  gattn_cos_k<<<BB / 4, 128, 0, stream>>>(finalS_b, gate2, node_batch, NO, h_n, outp);
}

// Round 16
// 351.578 us; speedup vs baseline: 1.0295x; 1.0295x over previous
//
#include <hip/hip_runtime.h>
#include <hip/hip_bf16.h>
#include <math.h>

// Problem dims (fixed by reference)
#define BB   256      // batch
#define LDE  64       // desc tokens len
#define NO   10240    // outer nodes
#define LO   32       // x tokens len
#define NM   81920    // mini nodes
#define LM   16       // mini tokens len
#define EO   81920    // outer edges
#define EM   327680   // mini edges
#define ED   128      // embed dim E
#define HIDD 256      // hidden
#define NH   8        // heads
#define DH   16       // head dim
#define VV   10000    // vocab

static inline int nblk(long long n, int b) { return (int)((n + b - 1) / b); }

typedef __attribute__((ext_vector_type(8))) short short8;
typedef __attribute__((ext_vector_type(4))) float f32x4;

// ---- fp32 <-> bf16 (RNE) helpers ----
static __device__ __forceinline__ unsigned short bf16_rne(float f) {
  unsigned u = __float_as_uint(f);
  return (unsigned short)((u + 0x7fffu + ((u >> 16) & 1u)) >> 16);
}
static __device__ __forceinline__ float bf16_to_f(unsigned short h) {
  return __uint_as_float(((unsigned)h) << 16);
}
static __device__ __forceinline__ float4 b4f(ushort4 h) {
  return make_float4(bf16_to_f(h.x), bf16_to_f(h.y), bf16_to_f(h.z), bf16_to_f(h.w));
}
static __device__ __forceinline__ ushort4 f4b(float4 v) {
  return make_ushort4(bf16_rne(v.x), bf16_rne(v.y), bf16_rne(v.z), bf16_rne(v.w));
}

// ============ merged conversion kernel: 6 weights -> split-bf16 frags, 2 tables -> bf16
struct WC { const float* W; int K, M; short8* hi; short8* lo; int base; };
struct WC6 { WC w[6]; };
__global__ void __launch_bounds__(256)
conv_all_k(WC6 wc, const float* __restrict__ t1, unsigned short* __restrict__ o1,
           const float* __restrict__ t2, unsigned short* __restrict__ o2) {
  if (blockIdx.x < 64) {
    int g = blockIdx.x * 256 + threadIdx.x;   // octet id, 0..16383
    int wi = 0;
    #pragma unroll
    for (int i = 1; i < 6; ++i) if (g >= wc.w[i].base) wi = i;
    const WC c = wc.w[wi];
    int idx = g - c.base;
    int lane = idx & 63;
    int nt = (idx >> 6) % (c.M / 16);
    int kb = (idx >> 6) / (c.M / 16);
    int n = nt * 16 + (lane & 15);
    int k0 = kb * 32 + ((lane >> 4) << 3);
    short8 h, l;
    #pragma unroll
    for (int j = 0; j < 8; ++j) {
      float v = c.W[(size_t)(k0 + j) * c.M + n];
      unsigned short hb = bf16_rne(v);
      h[j] = (short)hb;
      l[j] = (short)bf16_rne(v - bf16_to_f(hb));
    }
    c.hi[idx] = h; c.lo[idx] = l;
  } else {
    int q = (blockIdx.x - 64) * 256 + threadIdx.x;   // quad id
    const int NT = VV * ED / 4;                       // 320000 per table
    if (q < NT) {
      float4 v = *(const float4*)(t1 + (size_t)q * 4);
      *(ushort4*)(o1 + (size_t)q * 4) = f4b(v);
    } else if (q < 2 * NT) {
      int q2 = q - NT;
      float4 v = *(const float4*)(t2 + (size_t)q2 * 4);
      *(ushort4*)(o2 + (size_t)q2 * 4) = f4b(v);
    }
  }
}

// ---- embedding masked mean body: 256 thr = 8 rows x 32 4-elem lanes ----
template<int L, bool TBF, bool OUTBF>
static __device__ __forceinline__ void embed_body(const int* __restrict__ tokens,
                                                  const void* __restrict__ table,
                                                  void* __restrict__ out, int blk) {
  const int r = threadIdx.x >> 5, lane = threadIdx.x & 31;
  const int n0 = blk * 8;
  __shared__ int toks[8][L];
  for (int i = threadIdx.x; i < 8 * L; i += 256)
    toks[i / L][i % L] = tokens[(size_t)n0 * L + i];
  __syncthreads();
  float4 acc = make_float4(0.f, 0.f, 0.f, 0.f);
  int cnt = 0;
  #pragma unroll
  for (int l = 0; l < L; ++l) {
    int t = toks[r][l];
    float4 v;
    if (TBF) v = b4f(*((const ushort4*)((const unsigned short*)table + (size_t)t * ED + lane * 4)));
    else     v = *(const float4*)((const float*)table + (size_t)t * ED + lane * 4);
    float msk = (t != 0) ? 1.f : 0.f;
    cnt += (t != 0);
    acc.x = fmaf(msk, v.x, acc.x); acc.y = fmaf(msk, v.y, acc.y);
    acc.z = fmaf(msk, v.z, acc.z); acc.w = fmaf(msk, v.w, acc.w);
  }
  float inv = 1.f / (float)(cnt > 0 ? cnt : 1);
  acc.x *= inv; acc.y *= inv; acc.z *= inv; acc.w *= inv;
  if (OUTBF)
    *(ushort4*)((unsigned short*)out + (size_t)(n0 + r) * ED + lane * 4) = f4b(acc);
  else
    *(float4*)((float*)out + (size_t)(n0 + r) * ED + lane * 4) = acc;
}

// all three embeddings in one launch
__global__ void __launch_bounds__(256)
embed_all_k(const int* __restrict__ desc_tokens, const float* __restrict__ desc_table,
            float* __restrict__ h_n,
            const int* __restrict__ x_tokens, const unsigned short* __restrict__ ctab2,
            unsigned short* __restrict__ stmt,
            const int* __restrict__ mini_tokens, const unsigned short* __restrict__ ctab,
            unsigned short* __restrict__ miniE) {
  int b = blockIdx.x;
  if (b < BB / 8) embed_body<LDE, false, false>(desc_tokens, desc_table, h_n, b);
  else if (b < BB / 8 + NO / 8) embed_body<LO, true, true>(x_tokens, ctab2, stmt, b - BB / 8);
  else embed_body<LM, true, true>(mini_tokens, ctab, miniE, b - BB / 8 - NO / 8);
}

// ========== QKVS GEMM v7: XCD-aware swizzle, single-term, 512 thr ==========
struct QDesc { const short8* bh; const float* bias; unsigned short* C; };
struct QDesc4 { QDesc d[4]; };

__global__ void __launch_bounds__(512)
mgemm_qkvs7_k(const unsigned short* __restrict__ Ab, QDesc4 g4) {
  const int id = blockIdx.x;
  const int mat = (id >> 3) & 3;
  const int rowb = (id & 7) | ((id >> 5) << 3);
  const QDesc d = g4.d[mat];
  const int n0 = rowb * 128;
  const int tid = threadIdx.x;
  const int w = tid >> 6, lane = tid & 63;
  const int wm = (w & 3) * 2;
  const int wn = (w >> 2) * 4;
  const int r = lane & 15, qd = lane >> 4;
  f32x4 acc[2][4];
  #pragma unroll
  for (int i = 0; i < 2; ++i)
    #pragma unroll
    for (int j = 0; j < 4; ++j) acc[i][j] = (f32x4){0.f, 0.f, 0.f, 0.f};
  #pragma unroll
  for (int kb = 0; kb < 4; ++kb) {
    short8 bh[4];
    #pragma unroll
    for (int j = 0; j < 4; ++j)
      bh[j] = d.bh[((size_t)kb * 8 + wn + j) * 64 + lane];
    short8 a[2];
    #pragma unroll
    for (int i = 0; i < 2; ++i)
      a[i] = *(const short8*)(Ab + (size_t)(n0 + (wm + i) * 16 + r) * ED + kb * 32 + qd * 8);
    #pragma unroll
    for (int i = 0; i < 2; ++i)
      #pragma unroll
      for (int j = 0; j < 4; ++j)
        acc[i][j] = __builtin_amdgcn_mfma_f32_16x16x32_bf16(a[i], bh[j], acc[i][j], 0, 0, 0);
  }
  #pragma unroll
  for (int i = 0; i < 2; ++i)
    #pragma unroll
    for (int j = 0; j < 4; ++j) {
      int col = (wn + j) * 16 + r;
      float bv = d.bias[col];
      #pragma unroll
      for (int rr = 0; rr < 4; ++rr) {
        int row = (wm + i) * 16 + qd * 4 + rr;
        d.C[(size_t)(n0 + row) * ED + col] = bf16_rne(acc[i][j][rr] + bv);
      }
    }
}

// ========== generic single-term bf16 GEMM: bf16 A (row-major) x frag-W -> bf16 C ======
template<bool RELU>
__global__ void __launch_bounds__(512)
mgemm_b_k(const unsigned short* __restrict__ Ab, const short8* __restrict__ Bh,
          const float* __restrict__ bias, unsigned short* __restrict__ C,
          int K, int M) {
  const int bn0 = blockIdx.x * 128;
  const int n0 = blockIdx.y * 128;
  const int tid = threadIdx.x;
  const int w = tid >> 6, lane = tid & 63;
  const int wm = (w & 3) * 2, wn = (w >> 2) * 4;
  const int r = lane & 15, qd = lane >> 4;
  const int NTm = M / 16;
  f32x4 acc[2][4];
  #pragma unroll
  for (int i = 0; i < 2; ++i)
    #pragma unroll
    for (int j = 0; j < 4; ++j) acc[i][j] = (f32x4){0.f, 0.f, 0.f, 0.f};
  const int kbn = K / 32;
  for (int kb = 0; kb < kbn; ++kb) {
    short8 bh[4];
    #pragma unroll
    for (int j = 0; j < 4; ++j)
      bh[j] = Bh[((size_t)kb * NTm + (bn0 >> 4) + wn + j) * 64 + lane];
    short8 a[2];
    #pragma unroll
    for (int i = 0; i < 2; ++i)
      a[i] = *(const short8*)(Ab + (size_t)(n0 + (wm + i) * 16 + r) * K + kb * 32 + qd * 8);
    #pragma unroll
    for (int i = 0; i < 2; ++i)
      #pragma unroll
      for (int j = 0; j < 4; ++j)
        acc[i][j] = __builtin_amdgcn_mfma_f32_16x16x32_bf16(a[i], bh[j], acc[i][j], 0, 0, 0);
  }
  #pragma unroll
  for (int i = 0; i < 2; ++i)
    #pragma unroll
    for (int j = 0; j < 4; ++j) {
      int col = bn0 + (wn + j) * 16 + r;
      float bv = bias ? bias[col] : 0.f;
      #pragma unroll
      for (int rr = 0; rr < 4; ++rr) {
        int row = n0 + (wm + i) * 16 + qd * 4 + rr;
        float v = acc[i][j][rr] + bv;
        if (RELU) v = fmaxf(v, 0.f);
        C[(size_t)row * M + col] = bf16_rne(v);
      }
    }
}

// ================= CSR build (merged scan chain) =================
__global__ void hist2_k(const int* __restrict__ dm, int* __restrict__ hm,
                        const int* __restrict__ dd, int* __restrict__ ho) {
  int e = blockIdx.x * 256 + threadIdx.x;
  if (e < EM) atomicAdd(&hm[dm[e]], 1);
  else { int e2 = e - EM; if (e2 < EO) atomicAdd(&ho[dd[e2]], 1); }
}
__global__ void chunk_sum_k(const int* __restrict__ hist, int* __restrict__ partials, int N) {
  __shared__ int sd[256];
  int i = blockIdx.x * 256 + threadIdx.x;
  sd[threadIdx.x] = (i < N) ? hist[i] : 0;
  __syncthreads();
  for (int s = 128; s > 0; s >>= 1) {
    if (threadIdx.x < s) sd[threadIdx.x] += sd[threadIdx.x + s];
    __syncthreads();
  }
  if (threadIdx.x == 0) partials[blockIdx.x] = sd[0];
}
__global__ void scan_partials2_k(int* __restrict__ p) {
  __shared__ int sd[512];
  int base = (blockIdx.x == 0) ? 0 : NM / 256;
  int B    = (blockIdx.x == 0) ? NM / 256 : NO / 256;
  int t = threadIdx.x;
  int v = (t < B) ? p[base + t] : 0;
  sd[t] = v; __syncthreads();
  for (int off = 1; off < 512; off <<= 1) {
    int a = (t >= off) ? sd[t - off] : 0;
    __syncthreads();
    sd[t] += a;
    __syncthreads();
  }
  if (t < B) p[base + t] = sd[t] - v;   // exclusive
}
__global__ void scan_final2_k(const int* __restrict__ hist, const int* __restrict__ partials,
                              int* __restrict__ offsm, int* __restrict__ curm,
                              int* __restrict__ offso, int* __restrict__ curo,
                              float* __restrict__ dinv) {
  __shared__ int sd[256];
  int i = blockIdx.x * 256 + threadIdx.x;
  int v = hist[i];
  sd[threadIdx.x] = v; __syncthreads();
  for (int off = 1; off < 256; off <<= 1) {
    int a = (threadIdx.x >= off) ? sd[threadIdx.x - off] : 0;
    __syncthreads();
    sd[threadIdx.x] += a;
    __syncthreads();
  }
  int excl = sd[threadIdx.x] - v + partials[blockIdx.x];
  if (i < NM) {
    offsm[i] = excl; curm[i] = excl;
    if (i == NM - 1) offsm[NM] = excl + v;
  } else {
    int i2 = i - NM;
    offso[i2] = excl; curo[i2] = excl;
    if (i2 == NO - 1) offso[NO] = excl + v;
    dinv[i2] = 1.f / sqrtf(1.f + (float)v);
  }
}
__global__ void scatter2_k(const int* __restrict__ sm, const int* __restrict__ dm,
                           int* __restrict__ cm, int* __restrict__ km,
                           const int* __restrict__ so, const int* __restrict__ dd,
                           int* __restrict__ co, int* __restrict__ ko) {
  int e = blockIdx.x * 256 + threadIdx.x;
  if (e < EM) {
    int pos = atomicAdd(&cm[dm[e]], 1);
    km[pos] = sm[e];
  } else {
    int e2 = e - EM;
    if (e2 < EO) {
      int pos = atomicAdd(&co[dd[e2]], 1);
      ko[pos] = so[e2];
    }
  }
}

// ============ fused TransformerConv: 32 lanes/node, chunk-4 (degree-matched) ============
// R15 post-mortem: dual-half chunk-8 wasted ~50% slots at mean degree 4. This is the
// proven R12 structure with bf16 IO: 128 thr = 4 nodes x 32 lanes, 4 edges in flight.
__global__ void __launch_bounds__(128)
attn_fused_k(unsigned short* qh, const unsigned short* __restrict__ kk,
             const unsigned short* __restrict__ vv, const unsigned short* __restrict__ skip,
             const int* __restrict__ offs, const int* __restrict__ csr,
             const float* __restrict__ Wg, const float* __restrict__ bg,
             float* __restrict__ gateOut) {
  const int g = threadIdx.x >> 5, lane = threadIdx.x & 31;
  const int n = blockIdx.x * 4 + g;
  float4 q = b4f(*(const ushort4*)(qh + (size_t)n * ED + lane * 4));
  int lo = offs[n], hi = offs[n + 1];
  float4 O = make_float4(0.f, 0.f, 0.f, 0.f);
  float m = -INFINITY, l = 0.f;
  for (int base = lo; base < hi; base += 4) {
    int rem = hi - base;                      // >= 1
    int sidx[4];
    #pragma unroll
    for (int i = 0; i < 4; ++i) sidx[i] = (i < rem) ? csr[base + i] : 0;
    ushort4 kr[4], vr[4];
    #pragma unroll
    for (int i = 0; i < 4; ++i) {
      kr[i] = *(const ushort4*)(kk + (size_t)sidx[i] * ED + lane * 4);
      vr[i] = *(const ushort4*)(vv + (size_t)sidx[i] * ED + lane * 4);
    }
    #pragma unroll
    for (int i = 0; i < 4; ++i) {
      float4 kt = b4f(kr[i]);
      float4 vt = b4f(vr[i]);
      float p = q.x * kt.x + q.y * kt.y + q.z * kt.z + q.w * kt.w;
      p += __shfl_xor(p, 1, 64);
      p += __shfl_xor(p, 2, 64);
      float sc = (i < rem) ? p * 0.25f : -INFINITY;   // 1/sqrt(Dh); pad = no-op
      float mn = fmaxf(m, sc);
      float scale = __expf(m - mn);   // first real edge precedes any pad -> m finite
      float pe = __expf(sc - mn);
      l = l * scale + pe;
      O.x = O.x * scale + pe * vt.x; O.y = O.y * scale + pe * vt.y;
      O.z = O.z * scale + pe * vt.z; O.w = O.w * scale + pe * vt.w;
      m = mn;
    }
  }
  float inv = 1.f / (l + 1e-16f);
  float4 sk = b4f(*(const ushort4*)(skip + (size_t)n * ED + lane * 4));
  float4 out = make_float4(O.x * inv + sk.x, O.y * inv + sk.y,
                           O.z * inv + sk.z, O.w * inv + sk.w);
  *(ushort4*)(qh + (size_t)n * ED + lane * 4) = f4b(out);
  float4 wg = *(const float4*)(Wg + lane * 4);
  float ps = out.x * wg.x + out.y * wg.y + out.z * wg.z + out.w * wg.w;
  #pragma unroll
  for (int o = 1; o <= 16; o <<= 1) ps += __shfl_xor(ps, o, 64);
  if (lane == 0) gateOut[n] = ps + bg[0];
}

// ============ GCN gather (bf16): FULL WAVE per node, dual-half chunk-8 (deg 8) ========
__global__ void __launch_bounds__(256)
gcn_gather_b_k(const unsigned short* __restrict__ x, const float* __restrict__ dinv,
               const int* __restrict__ offs, const int* __restrict__ csr,
               const float* __restrict__ bias, unsigned short* __restrict__ out,
               const float* __restrict__ Wg, const float* __restrict__ bg,
               float* __restrict__ gateOut) {
  const int wv = threadIdx.x >> 6, lane = threadIdx.x & 63;
  const int half = lane >> 5, cl = lane & 31;
  const int n = blockIdx.x * 4 + wv;
  float di = dinv[n];
  float4 acc = make_float4(0.f, 0.f, 0.f, 0.f);
  if (half == 0) {   // self term once
    float4 xs = b4f(*(const ushort4*)(x + (size_t)n * ED + cl * 4));
    float w0 = di * di;
    acc = make_float4(w0 * xs.x, w0 * xs.y, w0 * xs.z, w0 * xs.w);
  }
  int lo = offs[n], hi = offs[n + 1];
  for (int base = lo; base < hi; base += 8) {
    int sidx[4]; bool ok[4];
    #pragma unroll
    for (int i = 0; i < 4; ++i) {
      int e = base + 2 * i + half;
      ok[i] = e < hi;
      sidx[i] = ok[i] ? csr[e] : 0;
    }
    float dw[4];
    #pragma unroll
    for (int i = 0; i < 4; ++i) dw[i] = ok[i] ? di * dinv[sidx[i]] : 0.f;
    ushort4 vr[4];
    #pragma unroll
    for (int i = 0; i < 4; ++i)
      vr[i] = *(const ushort4*)(x + (size_t)sidx[i] * ED + cl * 4);
    #pragma unroll
    for (int i = 0; i < 4; ++i) {
      float4 v = b4f(vr[i]);
      acc.x = fmaf(dw[i], v.x, acc.x); acc.y = fmaf(dw[i], v.y, acc.y);
      acc.z = fmaf(dw[i], v.z, acc.z); acc.w = fmaf(dw[i], v.w, acc.w);
    }
  }
  // merge halves
  acc.x += __shfl_xor(acc.x, 32, 64); acc.y += __shfl_xor(acc.y, 32, 64);
  acc.z += __shfl_xor(acc.z, 32, 64); acc.w += __shfl_xor(acc.w, 32, 64);
  if (bias) {
    float4 b4 = *(const float4*)(bias + cl * 4);
    acc.x += b4.x; acc.y += b4.y; acc.z += b4.z; acc.w += b4.w;
  }
  if (half == 0)
    *(ushort4*)(out + (size_t)n * ED + cl * 4) = f4b(acc);
  if (gateOut) {
    float4 wg = *(const float4*)(Wg + cl * 4);
    float ps = acc.x * wg.x + acc.y * wg.y + acc.z * wg.z + acc.w * wg.w;
    #pragma unroll
    for (int o = 1; o <= 16; o <<= 1) ps += __shfl_xor(ps, o, 64);
    if (lane == 0) gateOut[n] = ps + bg[0];
  }
}

// ============ global attention mini->NO (bf16 x/other/out) + combine ============
static __device__ __forceinline__ int lower_bound_d(const int* a, int n, int key) {
  int lo = 0, hi = n;
  while (lo < hi) { int mid = (lo + hi) >> 1; if (a[mid] < key) lo = mid + 1; else hi = mid; }
  return lo;
}
__global__ void __launch_bounds__(128)
gattn_comb_b_k(const unsigned short* __restrict__ xv, const float* __restrict__ gate,
               const int* __restrict__ seg, int Ntot,
               const unsigned short* __restrict__ other, unsigned short* __restrict__ out) {
  const int g = threadIdx.x >> 5, lane = threadIdx.x & 31;
  const int n = blockIdx.x * 4 + g;
  __shared__ int sh[4][2];
  if (lane == 0) {
    sh[g][0] = lower_bound_d(seg, Ntot, n);
    sh[g][1] = lower_bound_d(seg, Ntot, n + 1);
  }
  __syncthreads();
  int lo = sh[g][0], hi = sh[g][1];
  float m = -INFINITY;
  for (int j = lo; j < hi; ++j) m = fmaxf(m, gate[j]);
  float ssum = 0.f;
  for (int j = lo; j < hi; ++j) ssum += __expf(gate[j] - m);
  float inv = 1.f / (ssum + 1e-16f);
  float4 acc = make_float4(0.f, 0.f, 0.f, 0.f);
  for (int j = lo; j < hi; ++j) {
    float a = __expf(gate[j] - m) * inv;
    float4 v = b4f(*(const ushort4*)(xv + (size_t)j * ED + lane * 4));
    acc.x = fmaf(a, v.x, acc.x); acc.y = fmaf(a, v.y, acc.y);
    acc.z = fmaf(a, v.z, acc.z); acc.w = fmaf(a, v.w, acc.w);
  }
  float4 o4 = b4f(*(const ushort4*)(other + (size_t)n * ED + lane * 4));
  acc.x = (acc.x + o4.x) * 0.5f; acc.y = (acc.y + o4.y) * 0.5f;
  acc.z = (acc.z + o4.z) * 0.5f; acc.w = (acc.w + o4.w) * 0.5f;
  *(ushort4*)(out + (size_t)n * ED + lane * 4) = f4b(acc);
}

// ============ final global attention NO->BB (bf16 x) with cosine fused ====
__global__ void __launch_bounds__(128)
gattn_cos_k(const unsigned short* __restrict__ x, const float* __restrict__ gate,
            const int* __restrict__ seg, int Ntot,
            const float* __restrict__ hn, float* __restrict__ outp) {
  const int g = threadIdx.x >> 5, lane = threadIdx.x & 31;
  const int n = blockIdx.x * 4 + g;
  __shared__ int sh[4][2];
  if (lane == 0) {
    sh[g][0] = lower_bound_d(seg, Ntot, n);
    sh[g][1] = lower_bound_d(seg, Ntot, n + 1);
  }
  __syncthreads();
  int lo = sh[g][0], hi = sh[g][1];
  float m = -INFINITY;
  for (int j = lo; j < hi; ++j) m = fmaxf(m, gate[j]);
  float ssum = 0.f;
  for (int j = lo; j < hi; ++j) ssum += __expf(gate[j] - m);
  float inv = 1.f / (ssum + 1e-16f);
  float4 acc = make_float4(0.f, 0.f, 0.f, 0.f);
  for (int j = lo; j < hi; ++j) {
    float a = __expf(gate[j] - m) * inv;
    float4 v = b4f(*(const ushort4*)(x + (size_t)j * ED + lane * 4));
    acc.x = fmaf(a, v.x, acc.x); acc.y = fmaf(a, v.y, acc.y);
    acc.z = fmaf(a, v.z, acc.z); acc.w = fmaf(a, v.w, acc.w);
  }
  float4 hv = *(const float4*)(hn + (size_t)n * ED + lane * 4);
  float dot = acc.x * hv.x + acc.y * hv.y + acc.z * hv.z + acc.w * hv.w;
  float na  = acc.x * acc.x + acc.y * acc.y + acc.z * acc.z + acc.w * acc.w;
  float nb  = hv.x * hv.x + hv.y * hv.y + hv.z * hv.z + hv.w * hv.w;
  #pragma unroll
  for (int o = 1; o <= 16; o <<= 1) {
    dot += __shfl_xor(dot, o, 64);
    na  += __shfl_xor(na,  o, 64);
    nb  += __shfl_xor(nb,  o, 64);
  }
  if (lane == 0)
    outp[n] = dot / (fmaxf(sqrtf(na), 1e-8f) * fmaxf(sqrtf(nb), 1e-8f));
}

// ---- workspace layout (4-byte element offsets) ----
constexpr size_t OFF_HN    = 0;                                  // BB*ED
constexpr size_t OFF_STMT  = OFF_HN    + (size_t)BB * ED;        // NO*ED (bf16 in half)
constexpr size_t OFF_A     = OFF_STMT  + (size_t)NO * ED;        // NM*ED (miniE bf16 -> recycled)
constexpr size_t OFF_QHID  = OFF_A     + (size_t)NM * ED;        // NM*ED floats (bf16 q->hid in 1st half)
constexpr size_t OFF_CT    = OFF_QHID  + (size_t)NM * ED / 2;    // 2nd half of QHID: bf16 tables
constexpr size_t OFF_K     = OFF_QHID  + (size_t)NM * ED;        // NM*ED floats (bf16 k + bf16 skip)
constexpr size_t OFF_V     = OFF_K     + (size_t)NM * ED;        // NM*ED floats (bf16 v in 1st half)
constexpr size_t T0        = OFF_V     + (size_t)NM * ED;
constexpr size_t OFF_GATE  = T0;                                 // NM
constexpr size_t OFF_GATE2 = OFF_GATE  + (size_t)NM;             // NO
constexpr size_t OFF_DINV  = OFF_GATE2 + (size_t)NO;             // NO
constexpr size_t OFF_HISTM = OFF_DINV  + (size_t)NO;             // NM (int)
constexpr size_t OFF_HISTO = OFF_HISTM + (size_t)NM;             // NO (adjacent -> concat scan)
constexpr size_t OFF_OFFSM = OFF_HISTO + (size_t)NO;             // NM+1
constexpr size_t OFF_CURM  = OFF_OFFSM + (size_t)NM + 1;         // NM
constexpr size_t OFF_CSRM  = OFF_CURM  + (size_t)NM;             // EM
constexpr size_t OFF_OFFSO = OFF_CSRM  + (size_t)EM;             // NO+1
constexpr size_t OFF_CURO  = OFF_OFFSO + (size_t)NO + 1;         // NO
constexpr size_t OFF_CSRO  = OFF_CURO  + (size_t)NO;             // EO
constexpr size_t OFF_PART  = OFF_CSRO  + (size_t)EO;             // 512 (int)
constexpr size_t OFF_WFHI  = OFF_PART  + 512;                    // 65536 floats
constexpr size_t OFF_WFLO  = OFF_WFHI  + 65536;                  // 65536 floats
constexpr size_t WO_Q  = 0, WO_K = 2048, WO_V = 4096, WO_S = 6144, WO_W2 = 8192, WO_W3 = 12288;
// region-A recycling after attn (miniE dead): all bf16
constexpr size_t OFF_MFN   = OFF_A;                              // NO*ED (bf16)
constexpr size_t OFF_AGG   = OFF_MFN   + (size_t)NO * ED;        // NO*ED (bf16)
constexpr size_t OFF_H     = OFF_AGG   + (size_t)NO * ED;        // NO*HIDD (bf16)
constexpr size_t OFF_T     = OFF_H     + (size_t)NO * HIDD;      // NO*ED (bf16)
constexpr size_t OFF_FIN   = OFF_T     + (size_t)NO * ED;        // NO*ED (bf16)

extern "C" void kernel_launch(void* const* d_in, const int* in_sizes, int n_in,
                              void* d_out, int out_size, void* d_ws, size_t ws_size,
                              hipStream_t stream) {
  const int* desc_tokens = (const int*)d_in[0];
  const int* x_tokens    = (const int*)d_in[1];
  const int* mini_tokens = (const int*)d_in[2];
  const int* src         = (const int*)d_in[3];
  const int* dst         = (const int*)d_in[4];
  const int* mini_src    = (const int*)d_in[5];
  const int* mini_dst    = (const int*)d_in[6];
  const int* mini_batch  = (const int*)d_in[7];
  const int* node_batch  = (const int*)d_in[8];
  const float* desc_table  = (const float*)d_in[9];
  const float* code_table  = (const float*)d_in[10];
  const float* code_table2 = (const float*)d_in[11];
  const float* Wq = (const float*)d_in[12]; const float* bq = (const float*)d_in[13];
  const float* Wk = (const float*)d_in[14]; const float* bk = (const float*)d_in[15];
  const float* Wv = (const float*)d_in[16]; const float* bv = (const float*)d_in[17];
  const float* Wskip = (const float*)d_in[18]; const float* bskip = (const float*)d_in[19];
  const float* W2 = (const float*)d_in[20]; const float* b2 = (const float*)d_in[21];
  const float* W3 = (const float*)d_in[22]; const float* b3 = (const float*)d_in[23];
  const float* Wg = (const float*)d_in[24]; const float* bg = (const float*)d_in[25];

  float* ws = (float*)d_ws;
  float* h_n   = ws + OFF_HN;
  unsigned short* stmt_b  = (unsigned short*)(ws + OFF_STMT);
  unsigned short* miniE_b = (unsigned short*)(ws + OFF_A);    // bf16 [NM][128]
  unsigned short* qhid_b = (unsigned short*)(ws + OFF_QHID);  // q -> hid, bf16
  unsigned short* ctab_b  = (unsigned short*)(ws + OFF_CT);
  unsigned short* ctab2_b = (unsigned short*)(ws + OFF_CT + (size_t)VV * ED / 2);
  unsigned short* kbuf_b = (unsigned short*)(ws + OFF_K);     // k, bf16
  unsigned short* skip_b = kbuf_b + (size_t)NM * ED;          // skip, bf16 (2nd half)
  unsigned short* vbuf_b = (unsigned short*)(ws + OFF_V);     // v, bf16
  float* gate  = ws + OFF_GATE;
  float* gate2 = ws + OFF_GATE2;
  float* dinv  = ws + OFF_DINV;
  int* histm = (int*)(ws + OFF_HISTM);
  int* histo = (int*)(ws + OFF_HISTO);
  int* offsm = (int*)(ws + OFF_OFFSM);
  int* curm  = (int*)(ws + OFF_CURM);
  int* csrm  = (int*)(ws + OFF_CSRM);
  int* offso = (int*)(ws + OFF_OFFSO);
  int* curo  = (int*)(ws + OFF_CURO);
  int* csro  = (int*)(ws + OFF_CSRO);
  int* part  = (int*)(ws + OFF_PART);
  short8* wfhi = (short8*)(ws + OFF_WFHI);
  short8* wflo = (short8*)(ws + OFF_WFLO);
  unsigned short* mini_fn_b = (unsigned short*)(ws + OFF_MFN);
  unsigned short* aggb_b    = (unsigned short*)(ws + OFF_AGG);
  unsigned short* hbuf_b    = (unsigned short*)(ws + OFF_H);
  unsigned short* tbuf_b    = (unsigned short*)(ws + OFF_T);
  unsigned short* finalS_b  = (unsigned short*)(ws + OFF_FIN);
  float* outp    = (float*)d_out;

  // ---- all conversions in ONE launch: 6 weights + 2 tables ----
  WC6 wc;
  wc.w[0] = {Wq,    ED,   ED,   wfhi + WO_Q,  wflo + WO_Q,  (int)WO_Q};
  wc.w[1] = {Wk,    ED,   ED,   wfhi + WO_K,  wflo + WO_K,  (int)WO_K};
  wc.w[2] = {Wv,    ED,   ED,   wfhi + WO_V,  wflo + WO_V,  (int)WO_V};
  wc.w[3] = {Wskip, ED,   ED,   wfhi + WO_S,  wflo + WO_S,  (int)WO_S};
  wc.w[4] = {W2,    ED,   HIDD, wfhi + WO_W2, wflo + WO_W2, (int)WO_W2};
  wc.w[5] = {W3,    HIDD, ED,   wfhi + WO_W3, wflo + WO_W3, (int)WO_W3};
  conv_all_k<<<64 + nblk(2 * VV * ED / 4, 256), 256, 0, stream>>>(
      wc, code_table, ctab_b, code_table2, ctab2_b);

  // ---- CSR build: merged hist/scatter + single concat scan chain + fused dinv ----
  hipMemsetAsync(histm, 0, (size_t)(NM + NO) * 4, stream);
  hist2_k<<<nblk(EM + EO, 256), 256, 0, stream>>>(mini_dst, histm, dst, histo);
  chunk_sum_k<<<(NM + NO) / 256, 256, 0, stream>>>(histm, part, NM + NO);
  scan_partials2_k<<<2, 512, 0, stream>>>(part);
  scan_final2_k<<<(NM + NO) / 256, 256, 0, stream>>>(histm, part, offsm, curm,
                                                     offso, curo, dinv);
  scatter2_k<<<nblk(EM + EO, 256), 256, 0, stream>>>(mini_src, mini_dst, curm, csrm,
                                                     src, dst, curo, csro);

  // ---- all three embeddings in one launch ----
  embed_all_k<<<BB / 8 + NO / 8 + NM / 8, 256, 0, stream>>>(
      desc_tokens, desc_table, h_n, x_tokens, ctab2_b, stmt_b,
      mini_tokens, ctab_b, miniE_b);

  // ---- Q,K,V,Skip projections: single-term bf16 MFMA, XCD-swizzled 1D grid ----
  QDesc4 g4;
  g4.d[0] = {wfhi + WO_Q, bq,    qhid_b};
  g4.d[1] = {wfhi + WO_K, bk,    kbuf_b};
  g4.d[2] = {wfhi + WO_V, bv,    vbuf_b};
  g4.d[3] = {wfhi + WO_S, bskip, skip_b};
  mgemm_qkvs7_k<<<4 * (NM / 128), 512, 0, stream>>>(miniE_b, g4);

  // ---- fused transformer conv (32-lane chunk-4) + gate ----
  attn_fused_k<<<NM / 4, 128, 0, stream>>>(qhid_b, kbuf_b, vbuf_b, skip_b,
                                           offsm, csrm, Wg, bg, gate);

  // ---- global attention mini -> NO, fused with (x + stmt)*0.5 (all bf16) ----
  gattn_comb_b_k<<<NO / 4, 128, 0, stream>>>(qhid_b, gate, mini_batch, NM,
                                             stmt_b, mini_fn_b);

  // ---- GCN conv 1: agg = A_hat * mini_fn (bf16) ; h = relu(agg @ W2 + b2) (bf16) ----
  gcn_gather_b_k<<<NO / 4, 256, 0, stream>>>(mini_fn_b, dinv, offso, csro, nullptr,
                                             aggb_b, nullptr, nullptr, nullptr);
  { dim3 g(HIDD / 128, NO / 128);
    mgemm_b_k<true><<<g, 512, 0, stream>>>(aggb_b, wfhi + WO_W2, b2, hbuf_b, ED, HIDD); }

  // ---- GCN conv 2: t = h @ W3 (bf16) ; final = A_hat * t + b3 (+ gate2) ----
  { dim3 g(1, NO / 128);
    mgemm_b_k<false><<<g, 512, 0, stream>>>(hbuf_b, wfhi + WO_W3, nullptr, tbuf_b, HIDD, ED); }
  gcn_gather_b_k<<<NO / 4, 256, 0, stream>>>(tbuf_b, dinv, offso, csro, b3, finalS_b,
                                             Wg, bg, gate2);

  // ---- global attention NO -> BB with fused cosine -> d_out [BB] ----
  gattn_cos_k<<<BB / 4, 128, 0, stream>>>(finalS_b, gate2, node_batch, NO, h_n, outp);
}

// Round 17
// 342.401 us; speedup vs baseline: 1.0571x; 1.0268x over previous
//
#include <hip/hip_runtime.h>
#include <hip/hip_bf16.h>
#include <math.h>

// Problem dims (fixed by reference)
#define BB   256      // batch
#define LDE  64       // desc tokens len
#define NO   10240    // outer nodes
#define LO   32       // x tokens len
#define NM   81920    // mini nodes
#define LM   16       // mini tokens len
#define EO   81920    // outer edges
#define EM   327680   // mini edges
#define ED   128      // embed dim E
#define HIDD 256      // hidden
#define NH   8        // heads
#define DH   16       // head dim
#define VV   10000    // vocab

static inline int nblk(long long n, int b) { return (int)((n + b - 1) / b); }

typedef __attribute__((ext_vector_type(8))) short short8;
typedef __attribute__((ext_vector_type(4))) float f32x4;

// ---- fp32 <-> bf16 (RNE) helpers ----
static __device__ __forceinline__ unsigned short bf16_rne(float f) {
  unsigned u = __float_as_uint(f);
  return (unsigned short)((u + 0x7fffu + ((u >> 16) & 1u)) >> 16);
}
static __device__ __forceinline__ float bf16_to_f(unsigned short h) {
  return __uint_as_float(((unsigned)h) << 16);
}
static __device__ __forceinline__ float4 b4f(ushort4 h) {
  return make_float4(bf16_to_f(h.x), bf16_to_f(h.y), bf16_to_f(h.z), bf16_to_f(h.w));
}
static __device__ __forceinline__ ushort4 f4b(float4 v) {
  return make_ushort4(bf16_rne(v.x), bf16_rne(v.y), bf16_rne(v.z), bf16_rne(v.w));
}

// ============ merged conversion kernel: 6 weights -> bf16 frags, 2 tables -> bf16,
// ============ PLUS hist zeroing (folds the memset dispatch)
struct WC { const float* W; int K, M; short8* hi; short8* lo; int base; };
struct WC6 { WC w[6]; };
#define TBLK (2 * VV * ED / 4 / 256)      // 2500 table blocks
#define ZBLK ((NM + NO) / 256)            // 360 hist-zero blocks
__global__ void __launch_bounds__(256)
conv_all_k(WC6 wc, const float* __restrict__ t1, unsigned short* __restrict__ o1,
           const float* __restrict__ t2, unsigned short* __restrict__ o2,
           int* __restrict__ hist) {
  if (blockIdx.x < 64) {
    int g = blockIdx.x * 256 + threadIdx.x;   // octet id, 0..16383
    int wi = 0;
    #pragma unroll
    for (int i = 1; i < 6; ++i) if (g >= wc.w[i].base) wi = i;
    const WC c = wc.w[wi];
    int idx = g - c.base;
    int lane = idx & 63;
    int nt = (idx >> 6) % (c.M / 16);
    int kb = (idx >> 6) / (c.M / 16);
    int n = nt * 16 + (lane & 15);
    int k0 = kb * 32 + ((lane >> 4) << 3);
    short8 h, l;
    #pragma unroll
    for (int j = 0; j < 8; ++j) {
      float v = c.W[(size_t)(k0 + j) * c.M + n];
      unsigned short hb = bf16_rne(v);
      h[j] = (short)hb;
      l[j] = (short)bf16_rne(v - bf16_to_f(hb));
    }
    c.hi[idx] = h; c.lo[idx] = l;
  } else if (blockIdx.x < 64 + TBLK) {
    int q = (blockIdx.x - 64) * 256 + threadIdx.x;   // quad id
    const int NT = VV * ED / 4;                       // 320000 per table
    if (q < NT) {
      float4 v = *(const float4*)(t1 + (size_t)q * 4);
      *(ushort4*)(o1 + (size_t)q * 4) = f4b(v);
    } else if (q < 2 * NT) {
      int q2 = q - NT;
      float4 v = *(const float4*)(t2 + (size_t)q2 * 4);
      *(ushort4*)(o2 + (size_t)q2 * 4) = f4b(v);
    }
  } else {
    int i = (blockIdx.x - 64 - TBLK) * 256 + threadIdx.x;
    if (i < NM + NO) hist[i] = 0;
  }
}

// ---- embed: fp32-table body (desc): 256 thr = 8 rows x 32 float4-lanes ----
template<int L>
static __device__ __forceinline__ void embed_body_f(const int* __restrict__ tokens,
                                                    const float* __restrict__ table,
                                                    float* __restrict__ out, int blk) {
  const int r = threadIdx.x >> 5, lane = threadIdx.x & 31;
  const int n0 = blk * 8;
  __shared__ int toks[8][L];
  for (int i = threadIdx.x; i < 8 * L; i += 256)
    toks[i / L][i % L] = tokens[(size_t)n0 * L + i];
  __syncthreads();
  float4 acc = make_float4(0.f, 0.f, 0.f, 0.f);
  int cnt = 0;
  #pragma unroll
  for (int l = 0; l < L; ++l) {
    int t = toks[r][l];
    float4 v = *(const float4*)(table + (size_t)t * ED + lane * 4);
    float msk = (t != 0) ? 1.f : 0.f;
    cnt += (t != 0);
    acc.x = fmaf(msk, v.x, acc.x); acc.y = fmaf(msk, v.y, acc.y);
    acc.z = fmaf(msk, v.z, acc.z); acc.w = fmaf(msk, v.w, acc.w);
  }
  float inv = 1.f / (float)(cnt > 0 ? cnt : 1);
  acc.x *= inv; acc.y *= inv; acc.z *= inv; acc.w *= inv;
  *(float4*)(out + (size_t)(n0 + r) * ED + lane * 4) = acc;
}

// ---- embed: bf16-table body: 256 thr = 16 rows x 16 lanes, 16B loads/stores ----
template<int L>
static __device__ __forceinline__ void embed_body16(const int* __restrict__ tokens,
                                                    const unsigned short* __restrict__ table,
                                                    unsigned short* __restrict__ out, int blk) {
  const int r = threadIdx.x >> 4, lane = threadIdx.x & 15;
  const int n0 = blk * 16;
  __shared__ int toks[16][L];
  for (int i = threadIdx.x; i < 16 * L; i += 256)
    toks[i / L][i % L] = tokens[(size_t)n0 * L + i];
  __syncthreads();
  float acc[8] = {};
  int cnt = 0;
  #pragma unroll
  for (int l = 0; l < L; ++l) {
    int t = toks[r][l];
    short8 v = *(const short8*)(table + (size_t)t * ED + lane * 8);
    float msk = (t != 0) ? 1.f : 0.f;
    cnt += (t != 0);
    #pragma unroll
    for (int j = 0; j < 8; ++j)
      acc[j] = fmaf(msk, bf16_to_f((unsigned short)v[j]), acc[j]);
  }
  float inv = 1.f / (float)(cnt > 0 ? cnt : 1);
  short8 o;
  #pragma unroll
  for (int j = 0; j < 8; ++j) o[j] = (short)bf16_rne(acc[j] * inv);
  *(short8*)(out + (size_t)(n0 + r) * ED + lane * 8) = o;
}

// all three embeddings in one launch: [0,32) desc | [32,672) x | [672,5792) mini
__global__ void __launch_bounds__(256)
embed_all_k(const int* __restrict__ desc_tokens, const float* __restrict__ desc_table,
            float* __restrict__ h_n,
            const int* __restrict__ x_tokens, const unsigned short* __restrict__ ctab2,
            unsigned short* __restrict__ stmt,
            const int* __restrict__ mini_tokens, const unsigned short* __restrict__ ctab,
            unsigned short* __restrict__ miniE) {
  int b = blockIdx.x;
  if (b < BB / 8) embed_body_f<LDE>(desc_tokens, desc_table, h_n, b);
  else if (b < BB / 8 + NO / 16) embed_body16<LO>(x_tokens, ctab2, stmt, b - BB / 8);
  else embed_body16<LM>(mini_tokens, ctab, miniE, b - BB / 8 - NO / 16);
}

// ========== QKVS GEMM v8: XCD swizzle + generalized epilogue column mapping ==========
// K/V write interleaved into kv[n][256]: group c gets k at c*8+0..3, v at c*8+4..7.
struct QDesc { const short8* bh; const float* bias; unsigned short* C;
               int rstride; int gmul; int goff; };
struct QDesc4 { QDesc d[4]; };

__global__ void __launch_bounds__(512)
mgemm_qkvs8_k(const unsigned short* __restrict__ Ab, QDesc4 g4) {
  const int id = blockIdx.x;
  const int mat = (id >> 3) & 3;
  const int rowb = (id & 7) | ((id >> 5) << 3);
  const QDesc d = g4.d[mat];
  const int n0 = rowb * 128;
  const int tid = threadIdx.x;
  const int w = tid >> 6, lane = tid & 63;
  const int wm = (w & 3) * 2;
  const int wn = (w >> 2) * 4;
  const int r = lane & 15, qd = lane >> 4;
  f32x4 acc[2][4];
  #pragma unroll
  for (int i = 0; i < 2; ++i)
    #pragma unroll
    for (int j = 0; j < 4; ++j) acc[i][j] = (f32x4){0.f, 0.f, 0.f, 0.f};
  #pragma unroll
  for (int kb = 0; kb < 4; ++kb) {
    short8 bh[4];
    #pragma unroll
    for (int j = 0; j < 4; ++j)
      bh[j] = d.bh[((size_t)kb * 8 + wn + j) * 64 + lane];
    short8 a[2];
    #pragma unroll
    for (int i = 0; i < 2; ++i)
      a[i] = *(const short8*)(Ab + (size_t)(n0 + (wm + i) * 16 + r) * ED + kb * 32 + qd * 8);
    #pragma unroll
    for (int i = 0; i < 2; ++i)
      #pragma unroll
      for (int j = 0; j < 4; ++j)
        acc[i][j] = __builtin_amdgcn_mfma_f32_16x16x32_bf16(a[i], bh[j], acc[i][j], 0, 0, 0);
  }
  #pragma unroll
  for (int i = 0; i < 2; ++i)
    #pragma unroll
    for (int j = 0; j < 4; ++j) {
      int col = (wn + j) * 16 + r;
      int cidx = (col >> 2) * d.gmul + d.goff + (col & 3);
      float bv = d.bias[col];
      #pragma unroll
      for (int rr = 0; rr < 4; ++rr) {
        int row = (wm + i) * 16 + qd * 4 + rr;
        d.C[(size_t)(n0 + row) * d.rstride + cidx] = bf16_rne(acc[i][j][rr] + bv);
      }
    }
}

// ========== generic single-term bf16 GEMM: bf16 A (row-major) x frag-W -> bf16 C ======
template<bool RELU>
__global__ void __launch_bounds__(512)
mgemm_b_k(const unsigned short* __restrict__ Ab, const short8* __restrict__ Bh,
          const float* __restrict__ bias, unsigned short* __restrict__ C,
          int K, int M) {
  const int bn0 = blockIdx.x * 128;
  const int n0 = blockIdx.y * 128;
  const int tid = threadIdx.x;
  const int w = tid >> 6, lane = tid & 63;
  const int wm = (w & 3) * 2, wn = (w >> 2) * 4;
  const int r = lane & 15, qd = lane >> 4;
  const int NTm = M / 16;
  f32x4 acc[2][4];
  #pragma unroll
  for (int i = 0; i < 2; ++i)
    #pragma unroll
    for (int j = 0; j < 4; ++j) acc[i][j] = (f32x4){0.f, 0.f, 0.f, 0.f};
  const int kbn = K / 32;
  for (int kb = 0; kb < kbn; ++kb) {
    short8 bh[4];
    #pragma unroll
    for (int j = 0; j < 4; ++j)
      bh[j] = Bh[((size_t)kb * NTm + (bn0 >> 4) + wn + j) * 64 + lane];
    short8 a[2];
    #pragma unroll
    for (int i = 0; i < 2; ++i)
      a[i] = *(const short8*)(Ab + (size_t)(n0 + (wm + i) * 16 + r) * K + kb * 32 + qd * 8);
    #pragma unroll
    for (int i = 0; i < 2; ++i)
      #pragma unroll
      for (int j = 0; j < 4; ++j)
        acc[i][j] = __builtin_amdgcn_mfma_f32_16x16x32_bf16(a[i], bh[j], acc[i][j], 0, 0, 0);
  }
  #pragma unroll
  for (int i = 0; i < 2; ++i)
    #pragma unroll
    for (int j = 0; j < 4; ++j) {
      int col = bn0 + (wn + j) * 16 + r;
      float bv = bias ? bias[col] : 0.f;
      #pragma unroll
      for (int rr = 0; rr < 4; ++rr) {
        int row = n0 + (wm + i) * 16 + qd * 4 + rr;
        float v = acc[i][j][rr] + bv;
        if (RELU) v = fmaxf(v, 0.f);
        C[(size_t)row * M + col] = bf16_rne(v);
      }
    }
}

// ================= CSR build (merged scan chain) =================
__global__ void hist2_k(const int* __restrict__ dm, int* __restrict__ hm,
                        const int* __restrict__ dd, int* __restrict__ ho) {
  int e = blockIdx.x * 256 + threadIdx.x;
  if (e < EM) atomicAdd(&hm[dm[e]], 1);
  else { int e2 = e - EM; if (e2 < EO) atomicAdd(&ho[dd[e2]], 1); }
}
__global__ void chunk_sum_k(const int* __restrict__ hist, int* __restrict__ partials, int N) {
  __shared__ int sd[256];
  int i = blockIdx.x * 256 + threadIdx.x;
  sd[threadIdx.x] = (i < N) ? hist[i] : 0;
  __syncthreads();
  for (int s = 128; s > 0; s >>= 1) {
    if (threadIdx.x < s) sd[threadIdx.x] += sd[threadIdx.x + s];
    __syncthreads();
  }
  if (threadIdx.x == 0) partials[blockIdx.x] = sd[0];
}
__global__ void scan_partials2_k(int* __restrict__ p) {
  __shared__ int sd[512];
  int base = (blockIdx.x == 0) ? 0 : NM / 256;
  int B    = (blockIdx.x == 0) ? NM / 256 : NO / 256;
  int t = threadIdx.x;
  int v = (t < B) ? p[base + t] : 0;
  sd[t] = v; __syncthreads();
  for (int off = 1; off < 512; off <<= 1) {
    int a = (t >= off) ? sd[t - off] : 0;
    __syncthreads();
    sd[t] += a;
    __syncthreads();
  }
  if (t < B) p[base + t] = sd[t] - v;   // exclusive
}
__global__ void scan_final2_k(const int* __restrict__ hist, const int* __restrict__ partials,
                              int* __restrict__ offsm, int* __restrict__ curm,
                              int* __restrict__ offso, int* __restrict__ curo,
                              float* __restrict__ dinv) {
  __shared__ int sd[256];
  int i = blockIdx.x * 256 + threadIdx.x;
  int v = hist[i];
  sd[threadIdx.x] = v; __syncthreads();
  for (int off = 1; off < 256; off <<= 1) {
    int a = (threadIdx.x >= off) ? sd[threadIdx.x - off] : 0;
    __syncthreads();
    sd[threadIdx.x] += a;
    __syncthreads();
  }
  int excl = sd[threadIdx.x] - v + partials[blockIdx.x];
  if (i < NM) {
    offsm[i] = excl; curm[i] = excl;
    if (i == NM - 1) offsm[NM] = excl + v;
  } else {
    int i2 = i - NM;
    offso[i2] = excl; curo[i2] = excl;
    if (i2 == NO - 1) offso[NO] = excl + v;
    dinv[i2] = 1.f / sqrtf(1.f + (float)v);
  }
}
__global__ void scatter2_k(const int* __restrict__ sm, const int* __restrict__ dm,
                           int* __restrict__ cm, int* __restrict__ km,
                           const int* __restrict__ so, const int* __restrict__ dd,
                           int* __restrict__ co, int* __restrict__ ko) {
  int e = blockIdx.x * 256 + threadIdx.x;
  if (e < EM) {
    int pos = atomicAdd(&cm[dm[e]], 1);
    km[pos] = sm[e];
  } else {
    int e2 = e - EM;
    if (e2 < EO) {
      int pos = atomicAdd(&co[dd[e2]], 1);
      ko[pos] = so[e2];
    }
  }
}

// ============ fused TransformerConv: 32 lanes/node, chunk-4, INTERLEAVED KV ============
// kv[n][c*8+0..3] = k channels c*4.., kv[n][c*8+4..7] = v channels — ONE 16B load per
// edge per lane (was two 8B loads from separate arrays).
__global__ void __launch_bounds__(128)
attn_fused_k(unsigned short* qh, const unsigned short* __restrict__ kv,
             const unsigned short* __restrict__ skip,
             const int* __restrict__ offs, const int* __restrict__ csr,
             const float* __restrict__ Wg, const float* __restrict__ bg,
             float* __restrict__ gateOut) {
  const int g = threadIdx.x >> 5, lane = threadIdx.x & 31;
  const int n = blockIdx.x * 4 + g;
  float4 q = b4f(*(const ushort4*)(qh + (size_t)n * ED + lane * 4));
  int lo = offs[n], hi = offs[n + 1];
  float4 O = make_float4(0.f, 0.f, 0.f, 0.f);
  float m = -INFINITY, l = 0.f;
  for (int base = lo; base < hi; base += 4) {
    int rem = hi - base;                      // >= 1
    int sidx[4];
    #pragma unroll
    for (int i = 0; i < 4; ++i) sidx[i] = (i < rem) ? csr[base + i] : 0;
    short8 kvr[4];
    #pragma unroll
    for (int i = 0; i < 4; ++i)
      kvr[i] = *(const short8*)(kv + (size_t)sidx[i] * (2 * ED) + lane * 8);
    #pragma unroll
    for (int i = 0; i < 4; ++i) {
      float4 kt = make_float4(bf16_to_f((unsigned short)kvr[i][0]),
                              bf16_to_f((unsigned short)kvr[i][1]),
                              bf16_to_f((unsigned short)kvr[i][2]),
                              bf16_to_f((unsigned short)kvr[i][3]));
      float4 vt = make_float4(bf16_to_f((unsigned short)kvr[i][4]),
                              bf16_to_f((unsigned short)kvr[i][5]),
                              bf16_to_f((unsigned short)kvr[i][6]),
                              bf16_to_f((unsigned short)kvr[i][7]));
      float p = q.x * kt.x + q.y * kt.y + q.z * kt.z + q.w * kt.w;
      p += __shfl_xor(p, 1, 64);
      p += __shfl_xor(p, 2, 64);
      float sc = (i < rem) ? p * 0.25f : -INFINITY;   // 1/sqrt(Dh); pad = no-op
      float mn = fmaxf(m, sc);
      float scale = __expf(m - mn);   // first real edge precedes any pad -> m finite
      float pe = __expf(sc - mn);
      l = l * scale + pe;
      O.x = O.x * scale + pe * vt.x; O.y = O.y * scale + pe * vt.y;
      O.z = O.z * scale + pe * vt.z; O.w = O.w * scale + pe * vt.w;
      m = mn;
    }
  }
  float inv = 1.f / (l + 1e-16f);
  float4 sk = b4f(*(const ushort4*)(skip + (size_t)n * ED + lane * 4));
  float4 out = make_float4(O.x * inv + sk.x, O.y * inv + sk.y,
                           O.z * inv + sk.z, O.w * inv + sk.w);
  *(ushort4*)(qh + (size_t)n * ED + lane * 4) = f4b(out);
  float4 wg = *(const float4*)(Wg + lane * 4);
  float ps = out.x * wg.x + out.y * wg.y + out.z * wg.z + out.w * wg.w;
  #pragma unroll
  for (int o = 1; o <= 16; o <<= 1) ps += __shfl_xor(ps, o, 64);
  if (lane == 0) gateOut[n] = ps + bg[0];
}

// ============ GCN gather (bf16): FULL WAVE per node, dual-half chunk-8 (deg 8) ========
__global__ void __launch_bounds__(256)
gcn_gather_b_k(const unsigned short* __restrict__ x, const float* __restrict__ dinv,
               const int* __restrict__ offs, const int* __restrict__ csr,
               const float* __restrict__ bias, unsigned short* __restrict__ out,
               const float* __restrict__ Wg, const float* __restrict__ bg,
               float* __restrict__ gateOut) {
  const int wv = threadIdx.x >> 6, lane = threadIdx.x & 63;
  const int half = lane >> 5, cl = lane & 31;
  const int n = blockIdx.x * 4 + wv;
  float di = dinv[n];
  float4 acc = make_float4(0.f, 0.f, 0.f, 0.f);
  if (half == 0) {   // self term once
    float4 xs = b4f(*(const ushort4*)(x + (size_t)n * ED + cl * 4));
    float w0 = di * di;
    acc = make_float4(w0 * xs.x, w0 * xs.y, w0 * xs.z, w0 * xs.w);
  }
  int lo = offs[n], hi = offs[n + 1];
  for (int base = lo; base < hi; base += 8) {
    int sidx[4]; bool ok[4];
    #pragma unroll
    for (int i = 0; i < 4; ++i) {
      int e = base + 2 * i + half;
      ok[i] = e < hi;
      sidx[i] = ok[i] ? csr[e] : 0;
    }
    float dw[4];
    #pragma unroll
    for (int i = 0; i < 4; ++i) dw[i] = ok[i] ? di * dinv[sidx[i]] : 0.f;
    ushort4 vr[4];
    #pragma unroll
    for (int i = 0; i < 4; ++i)
      vr[i] = *(const ushort4*)(x + (size_t)sidx[i] * ED + cl * 4);
    #pragma unroll
    for (int i = 0; i < 4; ++i) {
      float4 v = b4f(vr[i]);
      acc.x = fmaf(dw[i], v.x, acc.x); acc.y = fmaf(dw[i], v.y, acc.y);
      acc.z = fmaf(dw[i], v.z, acc.z); acc.w = fmaf(dw[i], v.w, acc.w);
    }
  }
  // merge halves
  acc.x += __shfl_xor(acc.x, 32, 64); acc.y += __shfl_xor(acc.y, 32, 64);
  acc.z += __shfl_xor(acc.z, 32, 64); acc.w += __shfl_xor(acc.w, 32, 64);
  if (bias) {
    float4 b4 = *(const float4*)(bias + cl * 4);
    acc.x += b4.x; acc.y += b4.y; acc.z += b4.z; acc.w += b4.w;
  }
  if (half == 0)
    *(ushort4*)(out + (size_t)n * ED + cl * 4) = f4b(acc);
  if (gateOut) {
    float4 wg = *(const float4*)(Wg + cl * 4);
    float ps = acc.x * wg.x + acc.y * wg.y + acc.z * wg.z + acc.w * wg.w;
    #pragma unroll
    for (int o = 1; o <= 16; o <<= 1) ps += __shfl_xor(ps, o, 64);
    if (lane == 0) gateOut[n] = ps + bg[0];
  }
}

// ============ global attention mini->NO (bf16 x/other/out) + combine ============
static __device__ __forceinline__ int lower_bound_d(const int* a, int n, int key) {
  int lo = 0, hi = n;
  while (lo < hi) { int mid = (lo + hi) >> 1; if (a[mid] < key) lo = mid + 1; else hi = mid; }
  return lo;
}
__global__ void __launch_bounds__(128)
gattn_comb_b_k(const unsigned short* __restrict__ xv, const float* __restrict__ gate,
               const int* __restrict__ seg, int Ntot,
               const unsigned short* __restrict__ other, unsigned short* __restrict__ out) {
  const int g = threadIdx.x >> 5, lane = threadIdx.x & 31;
  const int n = blockIdx.x * 4 + g;
  __shared__ int sh[4][2];
  if (lane == 0) {
    sh[g][0] = lower_bound_d(seg, Ntot, n);
    sh[g][1] = lower_bound_d(seg, Ntot, n + 1);
  }
  __syncthreads();
  int lo = sh[g][0], hi = sh[g][1];
  float m = -INFINITY;
  for (int j = lo; j < hi; ++j) m = fmaxf(m, gate[j]);
  float ssum = 0.f;
  for (int j = lo; j < hi; ++j) ssum += __expf(gate[j] - m);
  float inv = 1.f / (ssum + 1e-16f);
  float4 acc = make_float4(0.f, 0.f, 0.f, 0.f);
  for (int j = lo; j < hi; ++j) {
    float a = __expf(gate[j] - m) * inv;
    float4 v = b4f(*(const ushort4*)(xv + (size_t)j * ED + lane * 4));
    acc.x = fmaf(a, v.x, acc.x); acc.y = fmaf(a, v.y, acc.y);
    acc.z = fmaf(a, v.z, acc.z); acc.w = fmaf(a, v.w, acc.w);
  }
  float4 o4 = b4f(*(const ushort4*)(other + (size_t)n * ED + lane * 4));
  acc.x = (acc.x + o4.x) * 0.5f; acc.y = (acc.y + o4.y) * 0.5f;
  acc.z = (acc.z + o4.z) * 0.5f; acc.w = (acc.w + o4.w) * 0.5f;
  *(ushort4*)(out + (size_t)n * ED + lane * 4) = f4b(acc);
}

// ============ final global attention NO->BB (bf16 x) with cosine fused ====
__global__ void __launch_bounds__(128)
gattn_cos_k(const unsigned short* __restrict__ x, const float* __restrict__ gate,
            const int* __restrict__ seg, int Ntot,
            const float* __restrict__ hn, float* __restrict__ outp) {
  const int g = threadIdx.x >> 5, lane = threadIdx.x & 31;
  const int n = blockIdx.x * 4 + g;
  __shared__ int sh[4][2];
  if (lane == 0) {
    sh[g][0] = lower_bound_d(seg, Ntot, n);
    sh[g][1] = lower_bound_d(seg, Ntot, n + 1);
  }
  __syncthreads();
  int lo = sh[g][0], hi = sh[g][1];
  float m = -INFINITY;
  for (int j = lo; j < hi; ++j) m = fmaxf(m, gate[j]);
  float ssum = 0.f;
  for (int j = lo; j < hi; ++j) ssum += __expf(gate[j] - m);
  float inv = 1.f / (ssum + 1e-16f);
  float4 acc = make_float4(0.f, 0.f, 0.f, 0.f);
  for (int j = lo; j < hi; ++j) {
    float a = __expf(gate[j] - m) * inv;
    float4 v = b4f(*(const ushort4*)(x + (size_t)j * ED + lane * 4));
    acc.x = fmaf(a, v.x, acc.x); acc.y = fmaf(a, v.y, acc.y);
    acc.z = fmaf(a, v.z, acc.z); acc.w = fmaf(a, v.w, acc.w);
  }
  float4 hv = *(const float4*)(hn + (size_t)n * ED + lane * 4);
  float dot = acc.x * hv.x + acc.y * hv.y + acc.z * hv.z + acc.w * hv.w;
  float na  = acc.x * acc.x + acc.y * acc.y + acc.z * acc.z + acc.w * acc.w;
  float nb  = hv.x * hv.x + hv.y * hv.y + hv.z * hv.z + hv.w * hv.w;
  #pragma unroll
  for (int o = 1; o <= 16; o <<= 1) {
    dot += __shfl_xor(dot, o, 64);
    na  += __shfl_xor(na,  o, 64);
    nb  += __shfl_xor(nb,  o, 64);
  }
  if (lane == 0)
    outp[n] = dot / (fmaxf(sqrtf(na), 1e-8f) * fmaxf(sqrtf(nb), 1e-8f));
}

// ---- workspace layout (4-byte element offsets) ----
constexpr size_t OFF_HN    = 0;                                  // BB*ED
constexpr size_t OFF_STMT  = OFF_HN    + (size_t)BB * ED;        // NO*ED (bf16 in half)
constexpr size_t OFF_A     = OFF_STMT  + (size_t)NO * ED;        // NM*ED (miniE bf16 -> recycled)
constexpr size_t OFF_QHID  = OFF_A     + (size_t)NM * ED;        // NM*ED floats (bf16 q->hid in 1st half)
constexpr size_t OFF_CT    = OFF_QHID  + (size_t)NM * ED / 2;    // 2nd half of QHID: bf16 tables
constexpr size_t OFF_K     = OFF_QHID  + (size_t)NM * ED;        // NM*ED floats = kv interleaved (full)
constexpr size_t OFF_V     = OFF_K     + (size_t)NM * ED;        // NM*ED floats (bf16 skip in 1st half)
constexpr size_t T0        = OFF_V     + (size_t)NM * ED;
constexpr size_t OFF_GATE  = T0;                                 // NM
constexpr size_t OFF_GATE2 = OFF_GATE  + (size_t)NM;             // NO
constexpr size_t OFF_DINV  = OFF_GATE2 + (size_t)NO;             // NO
constexpr size_t OFF_HISTM = OFF_DINV  + (size_t)NO;             // NM (int)
constexpr size_t OFF_HISTO = OFF_HISTM + (size_t)NM;             // NO (adjacent -> concat scan)
constexpr size_t OFF_OFFSM = OFF_HISTO + (size_t)NO;             // NM+1
constexpr size_t OFF_CURM  = OFF_OFFSM + (size_t)NM + 1;         // NM
constexpr size_t OFF_CSRM  = OFF_CURM  + (size_t)NM;             // EM
constexpr size_t OFF_OFFSO = OFF_CSRM  + (size_t)EM;             // NO+1
constexpr size_t OFF_CURO  = OFF_OFFSO + (size_t)NO + 1;         // NO
constexpr size_t OFF_CSRO  = OFF_CURO  + (size_t)NO;             // EO
constexpr size_t OFF_PART  = OFF_CSRO  + (size_t)EO;             // 512 (int)
constexpr size_t OFF_WFHI  = OFF_PART  + 512;                    // 65536 floats
constexpr size_t OFF_WFLO  = OFF_WFHI  + 65536;                  // 65536 floats
constexpr size_t WO_Q  = 0, WO_K = 2048, WO_V = 4096, WO_S = 6144, WO_W2 = 8192, WO_W3 = 12288;
// region-A recycling after attn (miniE dead): all bf16
constexpr size_t OFF_MFN   = OFF_A;                              // NO*ED (bf16)
constexpr size_t OFF_AGG   = OFF_MFN   + (size_t)NO * ED;        // NO*ED (bf16)
constexpr size_t OFF_H     = OFF_AGG   + (size_t)NO * ED;        // NO*HIDD (bf16)
constexpr size_t OFF_T     = OFF_H     + (size_t)NO * HIDD;      // NO*ED (bf16)
constexpr size_t OFF_FIN   = OFF_T     + (size_t)NO * ED;        // NO*ED (bf16)

extern "C" void kernel_launch(void* const* d_in, const int* in_sizes, int n_in,
                              void* d_out, int out_size, void* d_ws, size_t ws_size,
                              hipStream_t stream) {
  const int* desc_tokens = (const int*)d_in[0];
  const int* x_tokens    = (const int*)d_in[1];
  const int* mini_tokens = (const int*)d_in[2];
  const int* src         = (const int*)d_in[3];
  const int* dst         = (const int*)d_in[4];
  const int* mini_src    = (const int*)d_in[5];
  const int* mini_dst    = (const int*)d_in[6];
  const int* mini_batch  = (const int*)d_in[7];
  const int* node_batch  = (const int*)d_in[8];
  const float* desc_table  = (const float*)d_in[9];
  const float* code_table  = (const float*)d_in[10];
  const float* code_table2 = (const float*)d_in[11];
  const float* Wq = (const float*)d_in[12]; const float* bq = (const float*)d_in[13];
  const float* Wk = (const float*)d_in[14]; const float* bk = (const float*)d_in[15];
  const float* Wv = (const float*)d_in[16]; const float* bv = (const float*)d_in[17];
  const float* Wskip = (const float*)d_in[18]; const float* bskip = (const float*)d_in[19];
  const float* W2 = (const float*)d_in[20]; const float* b2 = (const float*)d_in[21];
  const float* W3 = (const float*)d_in[22]; const float* b3 = (const float*)d_in[23];
  const float* Wg = (const float*)d_in[24]; const float* bg = (const float*)d_in[25];

  float* ws = (float*)d_ws;
  float* h_n   = ws + OFF_HN;
  unsigned short* stmt_b  = (unsigned short*)(ws + OFF_STMT);
  unsigned short* miniE_b = (unsigned short*)(ws + OFF_A);    // bf16 [NM][128]
  unsigned short* qhid_b = (unsigned short*)(ws + OFF_QHID);  // q -> hid, bf16
  unsigned short* ctab_b  = (unsigned short*)(ws + OFF_CT);
  unsigned short* ctab2_b = (unsigned short*)(ws + OFF_CT + (size_t)VV * ED / 2);
  unsigned short* kv_b   = (unsigned short*)(ws + OFF_K);     // interleaved k/v [NM][256]
  unsigned short* skip_b = (unsigned short*)(ws + OFF_V);     // skip, bf16
  float* gate  = ws + OFF_GATE;
  float* gate2 = ws + OFF_GATE2;
  float* dinv  = ws + OFF_DINV;
  int* histm = (int*)(ws + OFF_HISTM);
  int* histo = (int*)(ws + OFF_HISTO);
  int* offsm = (int*)(ws + OFF_OFFSM);
  int* curm  = (int*)(ws + OFF_CURM);
  int* csrm  = (int*)(ws + OFF_CSRM);
  int* offso = (int*)(ws + OFF_OFFSO);
  int* curo  = (int*)(ws + OFF_CURO);
  int* csro  = (int*)(ws + OFF_CSRO);
  int* part  = (int*)(ws + OFF_PART);
  short8* wfhi = (short8*)(ws + OFF_WFHI);
  short8* wflo = (short8*)(ws + OFF_WFLO);
  unsigned short* mini_fn_b = (unsigned short*)(ws + OFF_MFN);
  unsigned short* aggb_b    = (unsigned short*)(ws + OFF_AGG);
  unsigned short* hbuf_b    = (unsigned short*)(ws + OFF_H);
  unsigned short* tbuf_b    = (unsigned short*)(ws + OFF_T);
  unsigned short* finalS_b  = (unsigned short*)(ws + OFF_FIN);
  float* outp    = (float*)d_out;

  // ---- conversions + hist zeroing in ONE launch ----
  WC6 wc;
  wc.w[0] = {Wq,    ED,   ED,   wfhi + WO_Q,  wflo + WO_Q,  (int)WO_Q};
  wc.w[1] = {Wk,    ED,   ED,   wfhi + WO_K,  wflo + WO_K,  (int)WO_K};
  wc.w[2] = {Wv,    ED,   ED,   wfhi + WO_V,  wflo + WO_V,  (int)WO_V};
  wc.w[3] = {Wskip, ED,   ED,   wfhi + WO_S,  wflo + WO_S,  (int)WO_S};
  wc.w[4] = {W2,    ED,   HIDD, wfhi + WO_W2, wflo + WO_W2, (int)WO_W2};
  wc.w[5] = {W3,    HIDD, ED,   wfhi + WO_W3, wflo + WO_W3, (int)WO_W3};
  conv_all_k<<<64 + TBLK + ZBLK, 256, 0, stream>>>(
      wc, code_table, ctab_b, code_table2, ctab2_b, histm);

  // ---- CSR build: merged hist/scatter + single concat scan chain + fused dinv ----
  hist2_k<<<nblk(EM + EO, 256), 256, 0, stream>>>(mini_dst, histm, dst, histo);
  chunk_sum_k<<<(NM + NO) / 256, 256, 0, stream>>>(histm, part, NM + NO);
  scan_partials2_k<<<2, 512, 0, stream>>>(part);
  scan_final2_k<<<(NM + NO) / 256, 256, 0, stream>>>(histm, part, offsm, curm,
                                                     offso, curo, dinv);
  scatter2_k<<<nblk(EM + EO, 256), 256, 0, stream>>>(mini_src, mini_dst, curm, csrm,
                                                     src, dst, curo, csro);

  // ---- all three embeddings in one launch (bf16 bodies use 16B loads) ----
  embed_all_k<<<BB / 8 + NO / 16 + NM / 16, 256, 0, stream>>>(
      desc_tokens, desc_table, h_n, x_tokens, ctab2_b, stmt_b,
      mini_tokens, ctab_b, miniE_b);

  // ---- Q,K,V,Skip projections: K/V interleaved epilogue, XCD-swizzled grid ----
  QDesc4 g4;
  g4.d[0] = {wfhi + WO_Q, bq,    qhid_b, ED,     4, 0};
  g4.d[1] = {wfhi + WO_K, bk,    kv_b,   2 * ED, 8, 0};
  g4.d[2] = {wfhi + WO_V, bv,    kv_b,   2 * ED, 8, 4};
  g4.d[3] = {wfhi + WO_S, bskip, skip_b, ED,     4, 0};
  mgemm_qkvs8_k<<<4 * (NM / 128), 512, 0, stream>>>(miniE_b, g4);

  // ---- fused transformer conv (32-lane chunk-4, interleaved kv) + gate ----
  attn_fused_k<<<NM / 4, 128, 0, stream>>>(qhid_b, kv_b, skip_b,
                                           offsm, csrm, Wg, bg, gate);

  // ---- global attention mini -> NO, fused with (x + stmt)*0.5 (all bf16) ----
  gattn_comb_b_k<<<NO / 4, 128, 0, stream>>>(qhid_b, gate, mini_batch, NM,
                                             stmt_b, mini_fn_b);

  // ---- GCN conv 1: agg = A_hat * mini_fn (bf16) ; h = relu(agg @ W2 + b2) (bf16) ----
  gcn_gather_b_k<<<NO / 4, 256, 0, stream>>>(mini_fn_b, dinv, offso, csro, nullptr,
                                             aggb_b, nullptr, nullptr, nullptr);
  { dim3 g(HIDD / 128, NO / 128);
    mgemm_b_k<true><<<g, 512, 0, stream>>>(aggb_b, wfhi + WO_W2, b2, hbuf_b, ED, HIDD); }

  // ---- GCN conv 2: t = h @ W3 (bf16) ; final = A_hat * t + b3 (+ gate2) ----
  { dim3 g(1, NO / 128);
    mgemm_b_k<false><<<g, 512, 0, stream>>>(hbuf_b, wfhi + WO_W3, nullptr, tbuf_b, HIDD, ED); }
  gcn_gather_b_k<<<NO / 4, 256, 0, stream>>>(tbuf_b, dinv, offso, csro, b3, finalS_b,
                                             Wg, bg, gate2);

  // ---- global attention NO -> BB with fused cosine -> d_out [BB] ----
  gattn_cos_k<<<BB / 4, 128, 0, stream>>>(finalS_b, gate2, node_batch, NO, h_n, outp);
}